// Round 6
// baseline (22804.413 us; speedup 1.0000x reference)
//
#include <hip/hip_runtime.h>
#include <hip/hip_bf16.h>
#include <math.h>

#define EPSF 1e-7f
#define MAXNRM 0.99999f

static constexpr int Bb = 16, Ss = 128, Hh = 512, Vv = 10000, Ll = 3;
static constexpr int Nn = Bb * Ss; // 2048

typedef __attribute__((ext_vector_type(8))) short short8v;
typedef __attribute__((ext_vector_type(4))) float f32x4;

__device__ inline float4 ld4(const float* p){ return *(const float4*)p; }
__device__ inline void st4(float* p, float4 v){ *(float4*)p = v; }
__device__ inline float dot4(float4 a, float4 b){ return a.x*b.x + a.y*b.y + a.z*b.z + a.w*b.w; }
__device__ inline float sigm(float x){ return 1.f/(1.f + expf(-x)); }
__device__ inline unsigned short f2bf(float f){
  __hip_bfloat16 h = __float2bfloat16(f);
  return __builtin_bit_cast(unsigned short, h);
}
__device__ inline float rsum64f(float v){
  v+=__shfl_xor(v,32); v+=__shfl_xor(v,16); v+=__shfl_xor(v,8);
  v+=__shfl_xor(v,4);  v+=__shfl_xor(v,2);  v+=__shfl_xor(v,1); return v;
}

// ---------------- pack W[l][j][k] -> bf16 MFMA B-fragments, streaming layout ----------------
// Wpk[l][mat][ct 32][kt 16][lane 64][8]; elem = W[j=ct*16+(lane&15)][k=kt*32+(lane>>4)*8+i]
// Each (l,mat,ct,kt) slice is 1KB contiguous -> one fully-coalesced wave load.
__global__ void k_pack2(const float* __restrict__ Wr, const float* __restrict__ Wz,
                        const float* __restrict__ Wh, ushort* __restrict__ Wpk){
  int ct = blockIdx.x, lm = blockIdx.y;      // lm = l*3+mat
  int l = lm/3, mat = lm%3;
  const float* W = (mat==0?Wr:mat==1?Wz:Wh) + (size_t)l*Hh*Hh;
  int tid = threadIdx.x;
  int kt = tid>>6, lane = tid&63, q = lane>>4, nl = lane&15;
  int j = ct*16 + nl;
  int k0 = kt*32 + q*8;
  const float* src = W + (size_t)j*Hh + k0;
  union { ushort u[8]; uint4 v; } tmp;
  #pragma unroll
  for(int i=0;i<8;i++) tmp.u[i] = f2bf(src[i]);
  size_t off = ((((size_t)lm*32 + ct)*16 + kt)*64 + lane)*8;
  *(uint4*)(Wpk + off) = tmp.v;
}

// ---------------- per-(t,b) input-only dots ----------------
__global__ void k_predots(const float* __restrict__ XR, const float* __restrict__ XZ,
                          const float* __restrict__ XH,
                          const float* __restrict__ br, const float* __restrict__ bz,
                          const float* __restrict__ bh, float* __restrict__ pubX){
  int n = blockIdx.x; int tid = threadIdx.x; // 128 threads
  float s0=0,s1=0,s2=0,s3=0,s4=0,s5=0;
  for(int i=tid;i<Hh;i+=128){
    float xr=XR[(size_t)n*Hh+i], xz=XZ[(size_t)n*Hh+i], xh=XH[(size_t)n*Hh+i];
    s0+=xr*xr; s1+=xr*br[i]; s2+=xz*xz; s3+=xz*bz[i]; s4+=xh*xh; s5+=xh*bh[i];
  }
  __shared__ float red[2][6];
  s0=rsum64f(s0); s1=rsum64f(s1); s2=rsum64f(s2);
  s3=rsum64f(s3); s4=rsum64f(s4); s5=rsum64f(s5);
  int w = tid>>6;
  if((tid&63)==0){ red[w][0]=s0; red[w][1]=s1; red[w][2]=s2; red[w][3]=s3; red[w][4]=s4; red[w][5]=s5; }
  __syncthreads();
  if(tid==0){
    #pragma unroll
    for(int d=0;d<6;d++) pubX[(size_t)n*6+d] = red[0][d]+red[1][d];
  }
}

// ---------------- per-vocab constants ----------------
__global__ void k_pav(const float* __restrict__ P, const float* __restrict__ A,
                      float* __restrict__ pp, float* __restrict__ aa, float* __restrict__ pa){
  int w = threadIdx.x >> 6, lane = threadIdx.x & 63;
  int v = blockIdx.x*4 + w;
  const float4* Pr = (const float4*)(P + (size_t)v*Hh);
  const float4* Ar = (const float4*)(A + (size_t)v*Hh);
  float sp=0, sa=0, spa=0;
  #pragma unroll
  for(int i=0;i<2;i++){
    int k4 = lane*2 + i;
    float4 pv = Pr[k4], av = Ar[k4];
    sp += dot4(pv,pv); sa += dot4(av,av); spa += dot4(pv,av);
  }
  for(int o=32;o;o>>=1){ sp+=__shfl_down(sp,o); sa+=__shfl_down(sa,o); spa+=__shfl_down(spa,o); }
  if(lane==0){ pp[v]=sp; aa[v]=sqrtf(sa+EPSF); pa[v]=spa; }
}

// ---------------- embedding gather ----------------
__global__ void k_embed(const int* __restrict__ inp, const float* __restrict__ E, float* __restrict__ X){
  int n = blockIdx.x; int t = n >> 4, b = n & 15;
  int tok = inp[b*Ss + t];
  int i = threadIdx.x;
  st4(X + (size_t)n*Hh + i*4, ld4(E + (size_t)tok*Hh + i*4));
}

// ---------------- row logmap0 ----------------
__global__ void k_logmap(const float* __restrict__ X, float* __restrict__ LX){
  int n = blockIdx.x; int t = threadIdx.x;
  __shared__ float sred[2];
  float4 v = ld4(X + (size_t)n*Hh + t*4);
  float ss = dot4(v,v);
  for(int o=32;o;o>>=1) ss += __shfl_down(ss,o);
  if((t&63)==0) sred[t>>6] = ss;
  __syncthreads();
  ss = sred[0]+sred[1];
  float nn = sqrtf(ss + EPSF);
  float sc = atanhf(fminf(nn, MAXNRM)) / nn;
  v.x*=sc; v.y*=sc; v.z*=sc; v.w*=sc;
  st4(LX + (size_t)n*Hh + t*4, v);
}

// ---------------- row expmap0 (in place, 3 buffers) ----------------
__global__ void k_expmap(float* __restrict__ XR, float* __restrict__ XZ, float* __restrict__ XH){
  float* Xp = blockIdx.y==0 ? XR : (blockIdx.y==1 ? XZ : XH);
  int n = blockIdx.x; int t = threadIdx.x;
  __shared__ float sred[2];
  float4 v = ld4(Xp + (size_t)n*Hh + t*4);
  float ss = dot4(v,v);
  for(int o=32;o;o>>=1) ss += __shfl_down(ss,o);
  if((t&63)==0) sred[t>>6] = ss;
  __syncthreads();
  ss = sred[0]+sred[1];
  float nn = sqrtf(ss + EPSF);
  float sc = tanhf(nn) / nn;
  v.x*=sc; v.y*=sc; v.z*=sc; v.w*=sc;
  st4(Xp + (size_t)n*Hh + t*4, v);
}

// ---------------- GEMM: LX[2048,512] @ {Ur|Uz|Uh}^T ----------------
__global__ __launch_bounds__(256) void k_gemm(const float* __restrict__ A4,
    const float* __restrict__ U0, const float* __restrict__ U1, const float* __restrict__ U2,
    float* __restrict__ O0, float* __restrict__ O1, float* __restrict__ O2){
  __shared__ float As[16][65], Bs[16][65];
  int jb = blockIdx.x;
  int nb = blockIdx.y;
  int mat = jb >> 3; int j0 = (jb & 7)*64;
  const float* Bm = mat==0?U0 : (mat==1?U1:U2);
  float* Om       = mat==0?O0 : (mat==1?O1:O2);
  int tid = threadIdx.x;
  int lr = tid >> 2, lq = tid & 3;
  int tx = tid & 15, ty = tid >> 4;
  float acc[4][4] = {};
  for(int kb=0; kb<Hh; kb+=16){
    float4 av = ld4(A4 + (size_t)(nb*64+lr)*Hh + kb + lq*4);
    float4 bv = ld4(Bm + (size_t)(j0+lr)*Hh + kb + lq*4);
    As[lq*4+0][lr]=av.x; As[lq*4+1][lr]=av.y; As[lq*4+2][lr]=av.z; As[lq*4+3][lr]=av.w;
    Bs[lq*4+0][lr]=bv.x; Bs[lq*4+1][lr]=bv.y; Bs[lq*4+2][lr]=bv.z; Bs[lq*4+3][lr]=bv.w;
    __syncthreads();
    #pragma unroll
    for(int kk=0;kk<16;kk++){
      float a0=As[kk][ty*4+0], a1=As[kk][ty*4+1], a2=As[kk][ty*4+2], a3=As[kk][ty*4+3];
      float b0=Bs[kk][tx*4+0], b1=Bs[kk][tx*4+1], b2=Bs[kk][tx*4+2], b3=Bs[kk][tx*4+3];
      acc[0][0]+=a0*b0; acc[0][1]+=a0*b1; acc[0][2]+=a0*b2; acc[0][3]+=a0*b3;
      acc[1][0]+=a1*b0; acc[1][1]+=a1*b1; acc[1][2]+=a1*b2; acc[1][3]+=a1*b3;
      acc[2][0]+=a2*b0; acc[2][1]+=a2*b1; acc[2][2]+=a2*b2; acc[2][3]+=a2*b3;
      acc[3][0]+=a3*b0; acc[3][1]+=a3*b1; acc[3][2]+=a3*b2; acc[3][3]+=a3*b3;
    }
    __syncthreads();
  }
  for(int i=0;i<4;i++)
    for(int j2=0;j2<4;j2++)
      Om[(size_t)(nb*64+ty*4+i)*Hh + j0 + tx*4 + j2] = acc[i][j2];
}

// ---------------- independent per-batch-row GRU scan, streaming-MFMA ----------------
// 16 blocks x 1024 threads; block b owns batch row b end-to-end. NO inter-block comms.
// Weights streamed from L2 (pre-packed MFMA B-frags); matvecs via MFMA with lh in A row 0.
__global__ __launch_bounds__(1024) void k_scan6(
    const float* __restrict__ XR, const float* __restrict__ XZ, const float* __restrict__ XH,
    const ushort* __restrict__ Wl,   // this layer: [mat][ct 32][kt 16][lane 64][8]
    const float* __restrict__ br, const float* __restrict__ bz, const float* __restrict__ bh,
    const float* __restrict__ pubX, float* __restrict__ Xout){
  const int b = blockIdx.x;
  const int tid = threadIdx.x;
  const int lane = tid & 63, wv = tid >> 6;   // 16 waves

  __shared__ ushort af[16*64*8];              // 16 KB A-frag (lh / ap), row 0 only
  __shared__ float mr_s[Hh], mz_s[Hh], mh_s[Hh];
  __shared__ float h_s[Hh], lh_s[Hh];
  __shared__ float bias0[Hh], bias1[Hh], bias2[Hh];
  __shared__ float partA[8][8];
  __shared__ float partB[8][18];
  __shared__ float coefA_s[8], coefB_s[8], bb_s[4];

  // init
  { uint4 z4={0,0,0,0}; ((uint4*)af)[tid] = z4; }   // 1024*16B = 16KB ✓
  if(tid<Hh){ h_s[tid]=0.f; lh_s[tid]=0.f; }
  for(int i=tid;i<Hh;i+=1024){ bias0[i]=br[i]; bias1[i]=bz[i]; bias2[i]=bh[i]; }
  __syncthreads();
  // bias grams (block-local)
  {
    float p0=0,p1=0,p2=0;
    if(tid<Hh){ float a=bias0[tid],b2=bias1[tid],c2=bias2[tid]; p0=a*a; p1=b2*b2; p2=c2*c2; }
    p0=rsum64f(p0); p1=rsum64f(p1); p2=rsum64f(p2);
    if(tid<Hh && (tid&63)==0){ partB[wv][0]=p0; partB[wv][1]=p1; partB[wv][2]=p2; }
    __syncthreads();
    if(tid==0){
      float a=0,b2=0,c2=0;
      for(int i=0;i<8;i++){ a+=partB[i][0]; b2+=partB[i][1]; c2+=partB[i][2]; }
      bb_s[0]=a; bb_s[1]=b2; bb_s[2]=c2;
    }
    __syncthreads();
  }

  float Sh = 0.f, hxh = 0.f, hbh = 0.f;   // live only on tid 0

  for(int ts=0; ts<Ss; ts++){
    const size_t row = (size_t)(ts*Bb + b)*Hh;

    // ---- P1: r/z matvecs. wave wv: col-tiles {2wv,2wv+1} x mats {r,z} ----
    for(int cc=0; cc<4; cc++){
      int mat = cc & 1;
      int ct  = wv*2 + (cc>>1);
      const ushort* base = Wl + ((((size_t)mat*32 + ct)*16)*64)*8;
      short8v frag[16];
      #pragma unroll
      for(int kt=0;kt<16;kt++)
        frag[kt] = *(const short8v*)(base + ((size_t)kt*64 + lane)*8);
      f32x4 acc = {0.f,0.f,0.f,0.f};
      #pragma unroll
      for(int kt=0;kt<16;kt++){
        short8v av = *(const short8v*)&af[((size_t)kt*64+lane)*8];
        acc = __builtin_amdgcn_mfma_f32_16x16x32_bf16(av, frag[kt], acc, 0,0,0);
      }
      if(lane<16) ((mat==0)? mr_s : mz_s)[ct*16+lane] = acc[0];
    }
    __syncthreads();

    // ---- P2: A-dots (8) over this row ----
    if(tid<Hh){
      float mr=mr_s[tid], mz=mz_s[tid], hv=h_s[tid];
      float xr=XR[row+tid], xz=XZ[row+tid], xh=XH[row+tid];
      float brc=bias0[tid], bzc=bias1[tid], bhc=bias2[tid];
      float p0=mr*mr, p1=mr*xr, p2=mr*brc, p3=mz*mz, p4=mz*xz, p5=mz*bzc, p6=hv*xh, p7=hv*bhc;
      p0=rsum64f(p0); p1=rsum64f(p1); p2=rsum64f(p2); p3=rsum64f(p3);
      p4=rsum64f(p4); p5=rsum64f(p5); p6=rsum64f(p6); p7=rsum64f(p7);
      if(lane==0){
        partA[wv][0]=p0; partA[wv][1]=p1; partA[wv][2]=p2; partA[wv][3]=p3;
        partA[wv][4]=p4; partA[wv][5]=p5; partA[wv][6]=p6; partA[wv][7]=p7;
      }
    }
    __syncthreads();

    // ---- P3: gate coefficients (thread 0) ----
    if(tid==0){
      float s[8];
      #pragma unroll
      for(int d=0;d<8;d++){
        float x=0;
        for(int i=0;i<8;i++) x+=partA[i][d];
        s[d]=x;
      }
      hxh=s[6]; hbh=s[7];
      const float* px = pubX + (size_t)(ts*Bb+b)*6;
      float xrxr=px[0], xrbr=px[1], xzxz=px[2], xzbz=px[3];
      float bbr=bb_s[0], bbz=bb_s[1];
      float nm=sqrtf(s[0]+EPSF), se=tanhf(nm)/nm;
      float uv=se*s[1], uu=se*se*s[0], vvr=xrxr;
      float den=1.f+2.f*uv+uu*vvr;
      float a1=(1.f+2.f*uv+vvr)*se/den, a2=(1.f-uu)/den;
      float uv2=a1*s[2]+a2*xrbr;
      float uu2=a1*a1*s[0]+2.f*a1*a2*s[1]+a2*a2*xrxr;
      float den2=1.f+2.f*uv2+uu2*bbr;
      float b1=(1.f+2.f*uv2+bbr)/den2, b2c=(1.f-uu2)/den2;
      float c1=b1*a1, c2=b1*a2, c3=b2c;
      float n2sq=c1*c1*s[0]+c2*c2*xrxr+c3*c3*bbr+2.f*(c1*c2*s[1]+c1*c3*s[2]+c2*c3*xrbr);
      float nn2=sqrtf(n2sq+EPSF);
      float s_r=atanhf(fminf(nn2,MAXNRM))/nn2;
      coefA_s[0]=s_r*c1; coefA_s[1]=s_r*c2; coefA_s[2]=s_r*c3;
      float nmz=sqrtf(s[3]+EPSF), sez=tanhf(nmz)/nmz;
      float uvz=sez*s[4], uuz=sez*sez*s[3], vvz=xzxz;
      float denz=1.f+2.f*uvz+uuz*vvz;
      float az1=(1.f+2.f*uvz+vvz)*sez/denz, az2=(1.f-uuz)/denz;
      float uvz2=az1*s[5]+az2*xzbz;
      float uuz2=az1*az1*s[3]+2.f*az1*az2*s[4]+az2*az2*xzxz;
      float denz2=1.f+2.f*uvz2+uuz2*bbz;
      float bz1=(1.f+2.f*uvz2+bbz)/denz2, bz2=(1.f-uuz2)/denz2;
      float cz1=bz1*az1, cz2=bz1*az2, cz3=bz2;
      float nz2sq=cz1*cz1*s[3]+cz2*cz2*xzxz+cz3*cz3*bbz+2.f*(cz1*cz2*s[4]+cz1*cz3*s[5]+cz2*cz3*xzbz);
      float nnz2=sqrtf(nz2sq+EPSF);
      float s_z=atanhf(fminf(nnz2,MAXNRM))/nnz2;
      coefA_s[3]=s_z*cz1; coefA_s[4]=s_z*cz2; coefA_s[5]=s_z*cz3;
    }
    __syncthreads();

    // ---- P4: build ap A-frag (threads 0..63, 8 elems each) ----
    if(tid<64){
      int kt = tid>>2, qq = tid&3;
      int e0 = tid*8;
      float ca=coefA_s[0], cb=coefA_s[1], cc2=coefA_s[2];
      short8v o;
      #pragma unroll
      for(int i=0;i<8;i++){
        int e = e0+i;
        float r1 = sigm(ca*mr_s[e] + cb*XR[row+e] + cc2*bias0[e]);
        o[i] = (short)f2bf(r1*lh_s[e]);
      }
      *(short8v*)&af[((size_t)kt*64 + qq*16)*8] = o;
    }
    __syncthreads();

    // ---- P5: h matvec. wave wv: col-tiles {2wv,2wv+1}, mat 2 ----
    for(int cc=0; cc<2; cc++){
      int ct = wv*2 + cc;
      const ushort* base = Wl + ((((size_t)2*32 + ct)*16)*64)*8;
      short8v frag[16];
      #pragma unroll
      for(int kt=0;kt<16;kt++)
        frag[kt] = *(const short8v*)(base + ((size_t)kt*64 + lane)*8);
      f32x4 acc = {0.f,0.f,0.f,0.f};
      #pragma unroll
      for(int kt=0;kt<16;kt++){
        short8v av = *(const short8v*)&af[((size_t)kt*64+lane)*8];
        acc = __builtin_amdgcn_mfma_f32_16x16x32_bf16(av, frag[kt], acc, 0,0,0);
      }
      if(lane<16) mh_s[ct*16+lane] = acc[0];
    }
    __syncthreads();

    // ---- P6: B-dots (18) ----
    if(tid<Hh){
      float mh=mh_s[tid], mz=mz_s[tid], hv=h_s[tid];
      float xh=XH[row+tid], xz=XZ[row+tid];
      float bhc=bias2[tid], bzc=bias1[tid];
      float z = sigm(coefA_s[3]*mz + coefA_s[4]*xz + coefA_s[5]*bzc);
      float eh=z*hv, em=z*mh, ex=z*xh, eb=z*bhc;
      float p[18] = {mh*mh, mh*xh, mh*bhc, hv*mh,
                     eh*eh, eh*em, eh*ex, eh*eb,
                     em*em, em*ex, em*eb, ex*ex, ex*eb, eb*eb,
                     hv*eh, hv*em, hv*ex, hv*eb};
      #pragma unroll
      for(int d=0;d<18;d++) p[d]=rsum64f(p[d]);
      if(lane==0){
        #pragma unroll
        for(int d=0;d<18;d++) partB[wv][d]=p[d];
      }
    }
    __syncthreads();

    // ---- P7: update coefficients (thread 0) ----
    if(tid==0){
      float dsum[18];
      #pragma unroll
      for(int d=0;d<18;d++){
        float x=0;
        for(int i=0;i<8;i++) x+=partB[i][d];
        dsum[d]=x;
      }
      float d0=dsum[0], d1=dsum[1], d2=dsum[2], d3=dsum[3];
      float Ghh=dsum[4], Ghm=dsum[5], Ghx=dsum[6], Ghb=dsum[7];
      float Gmm=dsum[8], Gmx=dsum[9], Gmb=dsum[10];
      float Gxx=dsum[11], Gxb=dsum[12], Gbb=dsum[13];
      float Heh=dsum[14], Hem=dsum[15], Hex=dsum[16], Heb=dsum[17];
      const float* px = pubX + (size_t)(ts*Bb+b)*6;
      float xhxh=px[4], xhbh=px[5];
      float bbh=bb_s[2]; float Shb=Sh;
      float nm3=sqrtf(d0+EPSF), se3=tanhf(nm3)/nm3;
      float uvh=se3*d1, uuh=se3*se3*d0, vvh=xhxh;
      float denh=1.f+2.f*uvh+uuh*vvh;
      float a1p=(1.f+2.f*uvh+vvh)*se3/denh, a2p=(1.f-uuh)/denh;
      float uv2h=a1p*d2+a2p*xhbh;
      float uu2h=a1p*a1p*d0+2.f*a1p*a2p*d1+a2p*a2p*xhxh;
      float den2h=1.f+2.f*uv2h+uu2h*bbh;
      float b1p=(1.f+2.f*uv2h+bbh)/den2h, b2p=(1.f-uu2h)/den2h;
      float c1p=b1p*a1p, c2p=b1p*a2p, c3p=b2p;
      float h_htil=c1p*d3+c2p*hxh+c3p*hbh;
      float htil2=c1p*c1p*d0+c2p*c2p*xhxh+c3p*c3p*bbh
                +2.f*(c1p*c2p*d1+c1p*c3p*d2+c2p*c3p*xhbh);
      float denD=1.f-2.f*h_htil+Shb*htil2;
      float dd1=(1.f-2.f*h_htil+htil2)/denD, dd2=(1.f-Shb)/denD;
      float g0=-dd1, g1=dd2*c1p, g2=dd2*c2p, g3=dd2*c3p;
      float del2=g0*g0*Shb+g1*g1*d0+g2*g2*xhxh+g3*g3*bbh
               +2.f*(g0*g1*d3+g0*g2*hxh+g0*g3*hbh+g1*g2*d1+g1*g3*d2+g2*g3*xhbh);
      float ndl=sqrtf(del2+EPSF);
      float sld=atanhf(fminf(ndl,MAXNRM))/ndl;
      float Qe=g0*g0*Ghh+g1*g1*Gmm+g2*g2*Gxx+g3*g3*Gbb
             +2.f*(g0*g1*Ghm+g0*g2*Ghx+g0*g3*Ghb+g1*g2*Gmx+g1*g3*Gmb+g2*g3*Gxb);
      float Le=g0*Heh+g1*Hem+g2*Hex+g3*Heb;
      float Sww=sld*sld*Qe;
      float Shw=sld*Le;
      float nw=sqrtf(Sww+EPSF), sew=tanhf(nw)/nw;
      float uvw=sew*Shw, uuw=Shb, vvw=sew*sew*Sww;
      float denw=1.f+2.f*uvw+uuw*vvw;
      float p1=(1.f+2.f*uvw+vvw)/denw, p2=(1.f-uuw)/denw;
      float q1=p1, q2=p2*sew;
      float n2h=q1*q1*Shb+2.f*q1*q2*Shw+q2*q2*Sww;
      float nrm=sqrtf(n2h+EPSF);
      float scl=fminf(1.f, MAXNRM/nrm);
      float Shn=scl*scl*n2h;
      float nh2=sqrtf(Shn+EPSF);
      float slh=atanhf(fminf(nh2,MAXNRM))/nh2;
      coefB_s[0]=scl*q1; coefB_s[1]=scl*q2*sld;
      coefB_s[2]=g0; coefB_s[3]=g1; coefB_s[4]=g2; coefB_s[5]=g3;
      coefB_s[6]=slh;
      Sh=Shn;
    }
    __syncthreads();

    // ---- P8: h update + write Xout + build lh A-frag (threads 0..63, 8 elems each) ----
    if(tid<64){
      int kt = tid>>2, qq = tid&3;
      int e0 = tid*8;
      float cz1=coefA_s[3], cz2=coefA_s[4], cz3=coefA_s[5];
      float qc1=coefB_s[0], qc2=coefB_s[1];
      float g0=coefB_s[2], g1=coefB_s[3], g2=coefB_s[4], g3=coefB_s[5];
      float slh=coefB_s[6];
      short8v o;
      f32x4 h0, h1;
      #pragma unroll
      for(int i=0;i<8;i++){
        int e = e0+i;
        float z  = sigm(cz1*mz_s[e] + cz2*XZ[row+e] + cz3*bias1[e]);
        float dl = g0*h_s[e] + g1*mh_s[e] + g2*XH[row+e] + g3*bias2[e];
        float hn = qc1*h_s[e] + qc2*z*dl;
        float lh = slh*hn;
        h_s[e]=hn; lh_s[e]=lh;
        o[i]=(short)f2bf(lh);
        if(i<4) h0[i]=hn; else h1[i-4]=hn;
      }
      *(short8v*)&af[((size_t)kt*64 + qq*16)*8] = o;
      *(f32x4*)(Xout + row + e0)     = h0;
      *(f32x4*)(Xout + row + e0 + 4) = h1;
    }
    __syncthreads();
  }
}

// ---------------- fused MLR + online softmax partials ----------------
__global__ __launch_bounds__(256) void k_mlr(const float* __restrict__ X,
    const float* __restrict__ P, const float* __restrict__ A,
    const float* __restrict__ pp, const float* __restrict__ aa, const float* __restrict__ pa,
    const int* __restrict__ tgt, float* __restrict__ pm, float* __restrict__ tl){
  constexpr int RT = 32;
  int split = blockIdx.x;      // 0..7
  int rg = blockIdx.y;         // 0..63
  int rbase = rg*RT;
  __shared__ float Xs[RT][516];
  __shared__ float par[8][RT];
  __shared__ float ms[8][RT][2];
  __shared__ float xxs[RT];
  int tid = threadIdx.x;
  #pragma unroll
  for(int u=0;u<16;u++){
    int fi = u*256 + tid;
    int row = fi >> 7, c4 = fi & 127;
    float4 v = ld4(X + (size_t)(rbase+row)*Hh + c4*4);
    st4(&Xs[row][c4*4], v);
  }
  __syncthreads();
  { int r = tid & 31, seg = tid >> 5;
    float s = 0;
    for(int k=seg*64;k<seg*64+64;k++){ float x = Xs[r][k]; s += x*x; }
    par[seg][r] = s; }
  __syncthreads();
  if(tid < RT){ float s=0; for(int i=0;i<8;i++) s += par[i][tid]; xxs[tid]=s; }
  __syncthreads();
  int r = tid & 31, vi = tid >> 5;
  int rr = rbase + r;
  int tt = rr >> 4, bbr2 = rr & 15;
  int tok = tgt[bbr2*Ss + tt];
  float xx = xxs[r];
  float m = -3.0e38f, sacc = 0.f;
  int v0 = split*1250, v1e = v0 + 1250;
  const float4* Xrow = (const float4*)&Xs[r][0];
  for(int vbv=v0; vbv<v1e; vbv+=8){
    int v = vbv + vi;
    if(v < v1e){
      float px=0, xa=0;
      const float4* Pr = (const float4*)(P + (size_t)v*Hh);
      const float4* Ar = (const float4*)(A + (size_t)v*Hh);
      #pragma unroll 4
      for(int k4=0;k4<128;k4++){
        float4 xv = Xrow[k4];
        float4 pvv = Pr[k4]; float4 av = Ar[k4];
        px += dot4(xv,pvv); xa += dot4(xv,av);
      }
      float ppv = pp[v], aav = aa[v], pav = pa[v];
      float al = 1.f - 2.f*px + xx;
      float be = 1.f - ppv;
      float gm = 1.f - 2.f*px + ppv*xx;
      float da = (-al*pav + be*xa)/gm;
      float dd = (al*al*ppv - 2.f*al*be*px + be*be*xx)/(gm*gm);
      float lam = 2.f/(1.f - ppv);
      float arg = 2.f*da/((1.f - dd)*aav + EPSF);
      float lg = lam*aav*asinhf(arg);
      if(v == tok) tl[rr] = lg;
      if(lg > m){ sacc = sacc*expf(m - lg) + 1.f; m = lg; }
      else sacc += expf(lg - m);
    }
  }
  ms[vi][r][0] = m; ms[vi][r][1] = sacc;
  __syncthreads();
  if(vi==0){
    float M = -3.0e38f;
    for(int i=0;i<8;i++) M = fmaxf(M, ms[i][r][0]);
    float Ssum = 0.f;
    for(int i=0;i<8;i++) Ssum += ms[i][r][1]*expf(ms[i][r][0]-M);
    pm[((size_t)rr*8 + split)*2 + 0] = M;
    pm[((size_t)rr*8 + split)*2 + 1] = Ssum;
  }
}

// ---------------- final merge + mean NLL ----------------
__global__ void k_final(const float* __restrict__ pm, const float* __restrict__ tl, float* __restrict__ out){
  int tid = threadIdx.x;
  __shared__ float sred[4];
  float acc = 0.f;
  for(int q=0;q<8;q++){
    int rr = q*256 + tid;
    float M = -3.0e38f;
    for(int s=0;s<8;s++) M = fmaxf(M, pm[((size_t)rr*8+s)*2]);
    float Ssum = 0.f;
    for(int s=0;s<8;s++) Ssum += pm[((size_t)rr*8+s)*2+1]*expf(pm[((size_t)rr*8+s)*2]-M);
    acc += (M + logf(Ssum)) - tl[rr];
  }
  for(int o=32;o;o>>=1) acc += __shfl_down(acc,o);
  if((tid&63)==0) sred[tid>>6] = acc;
  __syncthreads();
  if(tid==0) out[0] = (sred[0]+sred[1]+sred[2]+sred[3]) / 2048.f;
}

extern "C" void kernel_launch(void* const* d_in, const int* in_sizes, int n_in,
                              void* d_out, int out_size, void* d_ws, size_t ws_size,
                              hipStream_t stream){
  const int* inp = (const int*)d_in[0];
  const int* tgt = (const int*)d_in[1];
  const float* E  = (const float*)d_in[2];
  const float* Wr = (const float*)d_in[3];
  const float* Wz = (const float*)d_in[4];
  const float* Wh = (const float*)d_in[5];
  const float* Ur = (const float*)d_in[6];
  const float* Uz = (const float*)d_in[7];
  const float* Uh = (const float*)d_in[8];
  const float* br = (const float*)d_in[9];
  const float* bz = (const float*)d_in[10];
  const float* bh = (const float*)d_in[11];
  const float* P  = (const float*)d_in[12];
  const float* A  = (const float*)d_in[13];
  float* out = (float*)d_out;
  float* w = (float*)d_ws;
  size_t o = 0;
  auto take = [&](size_t n){ float* p = w + o; o += n; return p; };
  float* Xa  = take((size_t)Nn*Hh);
  float* Xb  = take((size_t)Nn*Hh);
  float* LX  = take((size_t)Nn*Hh);
  float* XR  = take((size_t)Nn*Hh);
  float* XZ  = take((size_t)Nn*Hh);
  float* XH  = take((size_t)Nn*Hh);
  ushort* Wpk = (ushort*)take(1179648);   // 9*32*16*64*8 bf16 = 2,359,296 ushorts
  float* pubX = take((size_t)Nn*6);
  float* pp  = take(10240);
  float* aa  = take(10240);
  float* pa  = take(10240);
  float* pm  = take((size_t)Nn*8*2);
  float* tl  = take((size_t)Nn);
  if(ws_size < o*sizeof(float)) return;

  hipLaunchKernelGGL(k_pack2, dim3(32,9), dim3(1024), 0, stream, Wr,Wz,Wh, Wpk);
  hipLaunchKernelGGL(k_pav, dim3(2500), dim3(256), 0, stream, P,A, pp,aa,pa);
  hipLaunchKernelGGL(k_embed, dim3(Nn), dim3(128), 0, stream, inp, E, Xa);
  float* cur = Xa; float* nxt = Xb;
  for(int l=0;l<Ll;l++){
    hipLaunchKernelGGL(k_logmap, dim3(Nn), dim3(128), 0, stream, cur, LX);
    hipLaunchKernelGGL(k_gemm, dim3(24,32), dim3(256), 0, stream, LX,
                       Ur + (size_t)l*Hh*Hh, Uz + (size_t)l*Hh*Hh, Uh + (size_t)l*Hh*Hh,
                       XR, XZ, XH);
    hipLaunchKernelGGL(k_expmap, dim3(Nn,3), dim3(128), 0, stream, XR,XZ,XH);
    hipLaunchKernelGGL(k_predots, dim3(Nn), dim3(128), 0, stream, XR,XZ,XH,
                       br + l*Hh, bz + l*Hh, bh + l*Hh, pubX);
    hipLaunchKernelGGL(k_scan6, dim3(Bb), dim3(1024), 0, stream, XR,XZ,XH,
                       Wpk + (size_t)l*3*32*16*64*8,
                       br + l*Hh, bz + l*Hh, bh + l*Hh, pubX, nxt);
    float* tmp = cur; cur = nxt; nxt = tmp;
  }
  hipLaunchKernelGGL(k_mlr, dim3(8,64), dim3(256), 0, stream, cur, P, A, pp,aa,pa, tgt, pm, tl);
  hipLaunchKernelGGL(k_final, dim3(1), dim3(256), 0, stream, pm, tl, out);
}

// Round 7
// 10944.166 us; speedup vs baseline: 2.0837x; 2.0837x over previous
//
#include <hip/hip_runtime.h>
#include <hip/hip_bf16.h>
#include <math.h>

#define EPSF 1e-7f
#define MAXNRM 0.99999f

static constexpr int Bb = 16, Ss = 128, Hh = 512, Vv = 10000, Ll = 3;
static constexpr int Nn = Bb * Ss; // 2048

typedef __attribute__((ext_vector_type(4))) float f32x4;

__device__ inline float4 ld4(const float* p){ return *(const float4*)p; }
__device__ inline void st4(float* p, float4 v){ *(float4*)p = v; }
__device__ inline float dot4(float4 a, float4 b){ return a.x*b.x + a.y*b.y + a.z*b.z + a.w*b.w; }
__device__ inline float sigm(float x){ return 1.f/(1.f + expf(-x)); }
__device__ inline unsigned short f2bf(float f){
  __hip_bfloat16 h = __float2bfloat16(f);
  return __builtin_bit_cast(unsigned short, h);
}
__device__ inline float bf_lo(unsigned u){ unsigned x = u << 16; return __builtin_bit_cast(float, x); }
__device__ inline float bf_hi(unsigned u){ unsigned x = u & 0xffff0000u; return __builtin_bit_cast(float, x); }
__device__ inline float rsum64f(float v){
  v+=__shfl_xor(v,32); v+=__shfl_xor(v,16); v+=__shfl_xor(v,8);
  v+=__shfl_xor(v,4);  v+=__shfl_xor(v,2);  v+=__shfl_xor(v,1); return v;
}

// ---------------- transpose W[l][j][k] -> bf16 Wt[l][k][j] ----------------
__global__ void k_transw(const float* __restrict__ Wr, const float* __restrict__ Wz,
                         const float* __restrict__ Wh,
                         ushort* __restrict__ Tr, ushort* __restrict__ Tz, ushort* __restrict__ Th){
  int z = blockIdx.z; int l = z % 3; int m = z / 3;
  const float* src = (m==0?Wr : m==1?Wz : Wh) + (size_t)l*Hh*Hh;
  ushort* dst      = (m==0?Tr : m==1?Tz : Th) + (size_t)l*Hh*Hh;
  __shared__ float tile[32][33];
  int x = blockIdx.x*32 + threadIdx.x;
  int y0 = blockIdx.y*32;
  for(int i=threadIdx.y;i<32;i+=8) tile[i][threadIdx.x] = src[(size_t)(y0+i)*Hh + x];
  __syncthreads();
  int xo = blockIdx.y*32 + threadIdx.x;
  int yo0 = blockIdx.x*32;
  for(int i=threadIdx.y;i<32;i+=8)
    dst[(size_t)(yo0+i)*Hh + xo] = f2bf(tile[threadIdx.x][i]);
}

// ---------------- per-(t,b) input-only dots ----------------
__global__ void k_predots(const float* __restrict__ XR, const float* __restrict__ XZ,
                          const float* __restrict__ XH,
                          const float* __restrict__ br, const float* __restrict__ bz,
                          const float* __restrict__ bh, float* __restrict__ pubX){
  int n = blockIdx.x; int tid = threadIdx.x; // 128 threads
  float s0=0,s1=0,s2=0,s3=0,s4=0,s5=0;
  for(int i=tid;i<Hh;i+=128){
    float xr=XR[(size_t)n*Hh+i], xz=XZ[(size_t)n*Hh+i], xh=XH[(size_t)n*Hh+i];
    s0+=xr*xr; s1+=xr*br[i]; s2+=xz*xz; s3+=xz*bz[i]; s4+=xh*xh; s5+=xh*bh[i];
  }
  __shared__ float red[2][6];
  s0=rsum64f(s0); s1=rsum64f(s1); s2=rsum64f(s2);
  s3=rsum64f(s3); s4=rsum64f(s4); s5=rsum64f(s5);
  int w = tid>>6;
  if((tid&63)==0){ red[w][0]=s0; red[w][1]=s1; red[w][2]=s2; red[w][3]=s3; red[w][4]=s4; red[w][5]=s5; }
  __syncthreads();
  if(tid==0){
    #pragma unroll
    for(int d=0;d<6;d++) pubX[(size_t)n*6+d] = red[0][d]+red[1][d];
  }
}

// ---------------- per-vocab constants ----------------
__global__ void k_pav(const float* __restrict__ P, const float* __restrict__ A,
                      float* __restrict__ pp, float* __restrict__ aa, float* __restrict__ pa){
  int w = threadIdx.x >> 6, lane = threadIdx.x & 63;
  int v = blockIdx.x*4 + w;
  const float4* Pr = (const float4*)(P + (size_t)v*Hh);
  const float4* Ar = (const float4*)(A + (size_t)v*Hh);
  float sp=0, sa=0, spa=0;
  #pragma unroll
  for(int i=0;i<2;i++){
    int k4 = lane*2 + i;
    float4 pv = Pr[k4], av = Ar[k4];
    sp += dot4(pv,pv); sa += dot4(av,av); spa += dot4(pv,av);
  }
  for(int o=32;o;o>>=1){ sp+=__shfl_down(sp,o); sa+=__shfl_down(sa,o); spa+=__shfl_down(spa,o); }
  if(lane==0){ pp[v]=sp; aa[v]=sqrtf(sa+EPSF); pa[v]=spa; }
}

// ---------------- embedding gather ----------------
__global__ void k_embed(const int* __restrict__ inp, const float* __restrict__ E, float* __restrict__ X){
  int n = blockIdx.x; int t = n >> 4, b = n & 15;
  int tok = inp[b*Ss + t];
  int i = threadIdx.x;
  st4(X + (size_t)n*Hh + i*4, ld4(E + (size_t)tok*Hh + i*4));
}

// ---------------- row logmap0 ----------------
__global__ void k_logmap(const float* __restrict__ X, float* __restrict__ LX){
  int n = blockIdx.x; int t = threadIdx.x;
  __shared__ float sred[2];
  float4 v = ld4(X + (size_t)n*Hh + t*4);
  float ss = dot4(v,v);
  for(int o=32;o;o>>=1) ss += __shfl_down(ss,o);
  if((t&63)==0) sred[t>>6] = ss;
  __syncthreads();
  ss = sred[0]+sred[1];
  float nn = sqrtf(ss + EPSF);
  float sc = atanhf(fminf(nn, MAXNRM)) / nn;
  v.x*=sc; v.y*=sc; v.z*=sc; v.w*=sc;
  st4(LX + (size_t)n*Hh + t*4, v);
}

// ---------------- row expmap0 (in place, 3 buffers) ----------------
__global__ void k_expmap(float* __restrict__ XR, float* __restrict__ XZ, float* __restrict__ XH){
  float* Xp = blockIdx.y==0 ? XR : (blockIdx.y==1 ? XZ : XH);
  int n = blockIdx.x; int t = threadIdx.x;
  __shared__ float sred[2];
  float4 v = ld4(Xp + (size_t)n*Hh + t*4);
  float ss = dot4(v,v);
  for(int o=32;o;o>>=1) ss += __shfl_down(ss,o);
  if((t&63)==0) sred[t>>6] = ss;
  __syncthreads();
  ss = sred[0]+sred[1];
  float nn = sqrtf(ss + EPSF);
  float sc = tanhf(nn) / nn;
  v.x*=sc; v.y*=sc; v.z*=sc; v.w*=sc;
  st4(Xp + (size_t)n*Hh + t*4, v);
}

// ---------------- GEMM: LX[2048,512] @ {Ur|Uz|Uh}^T ----------------
__global__ __launch_bounds__(256) void k_gemm(const float* __restrict__ A4,
    const float* __restrict__ U0, const float* __restrict__ U1, const float* __restrict__ U2,
    float* __restrict__ O0, float* __restrict__ O1, float* __restrict__ O2){
  __shared__ float As[16][65], Bs[16][65];
  int jb = blockIdx.x;
  int nb = blockIdx.y;
  int mat = jb >> 3; int j0 = (jb & 7)*64;
  const float* Bm = mat==0?U0 : (mat==1?U1:U2);
  float* Om       = mat==0?O0 : (mat==1?O1:O2);
  int tid = threadIdx.x;
  int lr = tid >> 2, lq = tid & 3;
  int tx = tid & 15, ty = tid >> 4;
  float acc[4][4] = {};
  for(int kb=0; kb<Hh; kb+=16){
    float4 av = ld4(A4 + (size_t)(nb*64+lr)*Hh + kb + lq*4);
    float4 bv = ld4(Bm + (size_t)(j0+lr)*Hh + kb + lq*4);
    As[lq*4+0][lr]=av.x; As[lq*4+1][lr]=av.y; As[lq*4+2][lr]=av.z; As[lq*4+3][lr]=av.w;
    Bs[lq*4+0][lr]=bv.x; Bs[lq*4+1][lr]=bv.y; Bs[lq*4+2][lr]=bv.z; Bs[lq*4+3][lr]=bv.w;
    __syncthreads();
    #pragma unroll
    for(int kk=0;kk<16;kk++){
      float a0=As[kk][ty*4+0], a1=As[kk][ty*4+1], a2=As[kk][ty*4+2], a3=As[kk][ty*4+3];
      float b0=Bs[kk][tx*4+0], b1=Bs[kk][tx*4+1], b2=Bs[kk][tx*4+2], b3=Bs[kk][tx*4+3];
      acc[0][0]+=a0*b0; acc[0][1]+=a0*b1; acc[0][2]+=a0*b2; acc[0][3]+=a0*b3;
      acc[1][0]+=a1*b0; acc[1][1]+=a1*b1; acc[1][2]+=a1*b2; acc[1][3]+=a1*b3;
      acc[2][0]+=a2*b0; acc[2][1]+=a2*b1; acc[2][2]+=a2*b2; acc[2][3]+=a2*b3;
      acc[3][0]+=a3*b0; acc[3][1]+=a3*b1; acc[3][2]+=a3*b2; acc[3][3]+=a3*b3;
    }
    __syncthreads();
  }
  for(int i=0;i<4;i++)
    for(int j2=0;j2<4;j2++)
      Om[(size_t)(nb*64+ty*4+i)*Hh + j0 + tx*4 + j2] = acc[i][j2];
}

// ---------------- independent per-batch-row GRU scan, wide-load streaming ----------------
// 16 blocks x 1024 threads; block b owns batch row b. Zero inter-block communication.
// Matvecs: thread owns 8 consecutive output cols, uint4 (8xbf16) loads, k-split partials.
__global__ __launch_bounds__(1024) void k_scan7(
    const float* __restrict__ XR, const float* __restrict__ XZ, const float* __restrict__ XH,
    const ushort* __restrict__ Tr, const ushort* __restrict__ Tz, const ushort* __restrict__ Th,
    const float* __restrict__ br, const float* __restrict__ bz, const float* __restrict__ bh,
    const float* __restrict__ pubX, float* __restrict__ Xout){
  const int b = blockIdx.x;
  const int tid = threadIdx.x;
  const int lane = tid & 63, wv = tid >> 6;   // 16 waves

  __shared__ float part[16][Hh];              // 32KB matvec partials
  __shared__ float mr_s[Hh], mz_s[Hh], mh_s[Hh];
  __shared__ float h_s[Hh], lh_s[Hh], ap_s[Hh];
  __shared__ float bias0[Hh], bias1[Hh], bias2[Hh];
  __shared__ float partA[8][8];
  __shared__ float partB[8][18];
  __shared__ float coefA_s[8], coefB_s[8], bb_s[4];

  // init
  if(tid<Hh){ h_s[tid]=0.f; lh_s[tid]=0.f; }
  for(int i=tid;i<Hh;i+=1024){ bias0[i]=br[i]; bias1[i]=bz[i]; bias2[i]=bh[i]; }
  __syncthreads();
  // bias grams (block-local)
  {
    float p0=0,p1=0,p2=0;
    if(tid<Hh){ float a=bias0[tid],b2=bias1[tid],c2=bias2[tid]; p0=a*a; p1=b2*b2; p2=c2*c2; }
    p0=rsum64f(p0); p1=rsum64f(p1); p2=rsum64f(p2);
    if(tid<Hh && lane==0){ partB[wv][0]=p0; partB[wv][1]=p1; partB[wv][2]=p2; }
    __syncthreads();
    if(tid==0){
      float a=0,b2=0,c2=0;
      for(int i=0;i<8;i++){ a+=partB[i][0]; b2+=partB[i][1]; c2+=partB[i][2]; }
      bb_s[0]=a; bb_s[1]=b2; bb_s[2]=c2;
    }
    __syncthreads();
  }

  float Sh = 0.f, hxh = 0.f, hbh = 0.f;   // live only on tid 0

  const int j8 = (tid & 63) * 8;          // 8 consecutive output cols

  for(int ts=0; ts<Ss; ts++){
    const size_t row = (size_t)(ts*Bb + b)*Hh;

    // ---- M1: mr (threads 0..511) / mz (512..1023); 8-way k-split, uint4 loads ----
    {
      int hf = tid >> 9;                  // 0 -> Tr, 1 -> Tz
      int kq = (tid >> 6) & 7;            // k-eighth (64 rows)
      const ushort* W = (hf ? Tz : Tr) + (size_t)(kq*64)*Hh + j8;
      f32x4 a0 = {0,0,0,0}, a1 = {0,0,0,0};
      #pragma unroll 8
      for(int kk=0; kk<64; kk++){
        uint4 w4 = *(const uint4*)(W + (size_t)kk*Hh);
        float l = lh_s[kq*64 + kk];
        a0[0]+=bf_lo(w4.x)*l; a0[1]+=bf_hi(w4.x)*l;
        a0[2]+=bf_lo(w4.y)*l; a0[3]+=bf_hi(w4.y)*l;
        a1[0]+=bf_lo(w4.z)*l; a1[1]+=bf_hi(w4.z)*l;
        a1[2]+=bf_lo(w4.w)*l; a1[3]+=bf_hi(w4.w)*l;
      }
      float* d = &part[hf*8+kq][j8];
      *(f32x4*)d = a0; *(f32x4*)(d+4) = a1;
    }
    __syncthreads();
    {
      int j = tid & 511;
      if(tid < 512){
        float s=0;
        #pragma unroll
        for(int q=0;q<8;q++) s += part[q][j];
        mr_s[j]=s;
      } else {
        float s=0;
        #pragma unroll
        for(int q=8;q<16;q++) s += part[q][j];
        mz_s[j]=s;
      }
    }
    __syncthreads();

    // ---- P2: A-dots (8) over this row ----
    if(tid<Hh){
      float mr=mr_s[tid], mz=mz_s[tid], hv=h_s[tid];
      float xr=XR[row+tid], xz=XZ[row+tid], xh=XH[row+tid];
      float brc=bias0[tid], bzc=bias1[tid], bhc=bias2[tid];
      float p0=mr*mr, p1=mr*xr, p2=mr*brc, p3=mz*mz, p4=mz*xz, p5=mz*bzc, p6=hv*xh, p7=hv*bhc;
      p0=rsum64f(p0); p1=rsum64f(p1); p2=rsum64f(p2); p3=rsum64f(p3);
      p4=rsum64f(p4); p5=rsum64f(p5); p6=rsum64f(p6); p7=rsum64f(p7);
      if(lane==0){
        partA[wv][0]=p0; partA[wv][1]=p1; partA[wv][2]=p2; partA[wv][3]=p3;
        partA[wv][4]=p4; partA[wv][5]=p5; partA[wv][6]=p6; partA[wv][7]=p7;
      }
    }
    __syncthreads();

    // ---- P3: gate coefficients (thread 0) ----
    if(tid==0){
      float s[8];
      #pragma unroll
      for(int d=0;d<8;d++){
        float x=0;
        for(int i=0;i<8;i++) x+=partA[i][d];
        s[d]=x;
      }
      hxh=s[6]; hbh=s[7];
      const float* px = pubX + (size_t)(ts*Bb+b)*6;
      float xrxr=px[0], xrbr=px[1], xzxz=px[2], xzbz=px[3];
      float bbr=bb_s[0], bbz=bb_s[1];
      float nm=sqrtf(s[0]+EPSF), se=tanhf(nm)/nm;
      float uv=se*s[1], uu=se*se*s[0], vvr=xrxr;
      float den=1.f+2.f*uv+uu*vvr;
      float a1=(1.f+2.f*uv+vvr)*se/den, a2=(1.f-uu)/den;
      float uv2=a1*s[2]+a2*xrbr;
      float uu2=a1*a1*s[0]+2.f*a1*a2*s[1]+a2*a2*xrxr;
      float den2=1.f+2.f*uv2+uu2*bbr;
      float b1=(1.f+2.f*uv2+bbr)/den2, b2c=(1.f-uu2)/den2;
      float c1=b1*a1, c2=b1*a2, c3=b2c;
      float n2sq=c1*c1*s[0]+c2*c2*xrxr+c3*c3*bbr+2.f*(c1*c2*s[1]+c1*c3*s[2]+c2*c3*xrbr);
      float nn2=sqrtf(n2sq+EPSF);
      float s_r=atanhf(fminf(nn2,MAXNRM))/nn2;
      coefA_s[0]=s_r*c1; coefA_s[1]=s_r*c2; coefA_s[2]=s_r*c3;
      float nmz=sqrtf(s[3]+EPSF), sez=tanhf(nmz)/nmz;
      float uvz=sez*s[4], uuz=sez*sez*s[3], vvz=xzxz;
      float denz=1.f+2.f*uvz+uuz*vvz;
      float az1=(1.f+2.f*uvz+vvz)*sez/denz, az2=(1.f-uuz)/denz;
      float uvz2=az1*s[5]+az2*xzbz;
      float uuz2=az1*az1*s[3]+2.f*az1*az2*s[4]+az2*az2*xzxz;
      float denz2=1.f+2.f*uvz2+uuz2*bbz;
      float bz1=(1.f+2.f*uvz2+bbz)/denz2, bz2=(1.f-uuz2)/denz2;
      float cz1=bz1*az1, cz2=bz1*az2, cz3=bz2;
      float nz2sq=cz1*cz1*s[3]+cz2*cz2*xzxz+cz3*cz3*bbz+2.f*(cz1*cz2*s[4]+cz1*cz3*s[5]+cz2*cz3*xzbz);
      float nnz2=sqrtf(nz2sq+EPSF);
      float s_z=atanhf(fminf(nnz2,MAXNRM))/nnz2;
      coefA_s[3]=s_z*cz1; coefA_s[4]=s_z*cz2; coefA_s[5]=s_z*cz3;
    }
    __syncthreads();

    // ---- P4: ap = r .* lh (threads 0..511) ----
    if(tid<Hh){
      float r1 = sigm(coefA_s[0]*mr_s[tid] + coefA_s[1]*XR[row+tid] + coefA_s[2]*bias0[tid]);
      ap_s[tid] = r1 * lh_s[tid];
    }
    __syncthreads();

    // ---- M2: mh, 16-way k-split (32 rows each), all 1024 threads ----
    {
      int ks = tid >> 6;                  // k-sixteenth
      const ushort* W = Th + (size_t)(ks*32)*Hh + j8;
      f32x4 a0 = {0,0,0,0}, a1 = {0,0,0,0};
      #pragma unroll 8
      for(int kk=0; kk<32; kk++){
        uint4 w4 = *(const uint4*)(W + (size_t)kk*Hh);
        float l = ap_s[ks*32 + kk];
        a0[0]+=bf_lo(w4.x)*l; a0[1]+=bf_hi(w4.x)*l;
        a0[2]+=bf_lo(w4.y)*l; a0[3]+=bf_hi(w4.y)*l;
        a1[0]+=bf_lo(w4.z)*l; a1[1]+=bf_hi(w4.z)*l;
        a1[2]+=bf_lo(w4.w)*l; a1[3]+=bf_hi(w4.w)*l;
      }
      float* d = &part[ks][j8];
      *(f32x4*)d = a0; *(f32x4*)(d+4) = a1;
    }
    __syncthreads();
    if(tid<Hh){
      float s=0;
      #pragma unroll
      for(int q=0;q<16;q++) s += part[q][tid];
      mh_s[tid]=s;
    }
    __syncthreads();

    // ---- P6: B-dots (18) ----
    if(tid<Hh){
      float mh=mh_s[tid], mz=mz_s[tid], hv=h_s[tid];
      float xh=XH[row+tid], xz=XZ[row+tid];
      float bhc=bias2[tid], bzc=bias1[tid];
      float z = sigm(coefA_s[3]*mz + coefA_s[4]*xz + coefA_s[5]*bzc);
      float eh=z*hv, em=z*mh, ex=z*xh, eb=z*bhc;
      float p[18] = {mh*mh, mh*xh, mh*bhc, hv*mh,
                     eh*eh, eh*em, eh*ex, eh*eb,
                     em*em, em*ex, em*eb, ex*ex, ex*eb, eb*eb,
                     hv*eh, hv*em, hv*ex, hv*eb};
      #pragma unroll
      for(int d=0;d<18;d++) p[d]=rsum64f(p[d]);
      if(lane==0){
        #pragma unroll
        for(int d=0;d<18;d++) partB[wv][d]=p[d];
      }
    }
    __syncthreads();

    // ---- P7: update coefficients (thread 0) ----
    if(tid==0){
      float dsum[18];
      #pragma unroll
      for(int d=0;d<18;d++){
        float x=0;
        for(int i=0;i<8;i++) x+=partB[i][d];
        dsum[d]=x;
      }
      float d0=dsum[0], d1=dsum[1], d2=dsum[2], d3=dsum[3];
      float Ghh=dsum[4], Ghm=dsum[5], Ghx=dsum[6], Ghb=dsum[7];
      float Gmm=dsum[8], Gmx=dsum[9], Gmb=dsum[10];
      float Gxx=dsum[11], Gxb=dsum[12], Gbb=dsum[13];
      float Heh=dsum[14], Hem=dsum[15], Hex=dsum[16], Heb=dsum[17];
      const float* px = pubX + (size_t)(ts*Bb+b)*6;
      float xhxh=px[4], xhbh=px[5];
      float bbh=bb_s[2]; float Shb=Sh;
      float nm3=sqrtf(d0+EPSF), se3=tanhf(nm3)/nm3;
      float uvh=se3*d1, uuh=se3*se3*d0, vvh=xhxh;
      float denh=1.f+2.f*uvh+uuh*vvh;
      float a1p=(1.f+2.f*uvh+vvh)*se3/denh, a2p=(1.f-uuh)/denh;
      float uv2h=a1p*d2+a2p*xhbh;
      float uu2h=a1p*a1p*d0+2.f*a1p*a2p*d1+a2p*a2p*xhxh;
      float den2h=1.f+2.f*uv2h+uu2h*bbh;
      float b1p=(1.f+2.f*uv2h+bbh)/den2h, b2p=(1.f-uu2h)/den2h;
      float c1p=b1p*a1p, c2p=b1p*a2p, c3p=b2p;
      float h_htil=c1p*d3+c2p*hxh+c3p*hbh;
      float htil2=c1p*c1p*d0+c2p*c2p*xhxh+c3p*c3p*bbh
                +2.f*(c1p*c2p*d1+c1p*c3p*d2+c2p*c3p*xhbh);
      float denD=1.f-2.f*h_htil+Shb*htil2;
      float dd1=(1.f-2.f*h_htil+htil2)/denD, dd2=(1.f-Shb)/denD;
      float g0=-dd1, g1=dd2*c1p, g2=dd2*c2p, g3=dd2*c3p;
      float del2=g0*g0*Shb+g1*g1*d0+g2*g2*xhxh+g3*g3*bbh
               +2.f*(g0*g1*d3+g0*g2*hxh+g0*g3*hbh+g1*g2*d1+g1*g3*d2+g2*g3*xhbh);
      float ndl=sqrtf(del2+EPSF);
      float sld=atanhf(fminf(ndl,MAXNRM))/ndl;
      float Qe=g0*g0*Ghh+g1*g1*Gmm+g2*g2*Gxx+g3*g3*Gbb
             +2.f*(g0*g1*Ghm+g0*g2*Ghx+g0*g3*Ghb+g1*g2*Gmx+g1*g3*Gmb+g2*g3*Gxb);
      float Le=g0*Heh+g1*Hem+g2*Hex+g3*Heb;
      float Sww=sld*sld*Qe;
      float Shw=sld*Le;
      float nw=sqrtf(Sww+EPSF), sew=tanhf(nw)/nw;
      float uvw=sew*Shw, uuw=Shb, vvw=sew*sew*Sww;
      float denw=1.f+2.f*uvw+uuw*vvw;
      float p1=(1.f+2.f*uvw+vvw)/denw, p2=(1.f-uuw)/denw;
      float q1=p1, q2=p2*sew;
      float n2h=q1*q1*Shb+2.f*q1*q2*Shw+q2*q2*Sww;
      float nrm=sqrtf(n2h+EPSF);
      float scl=fminf(1.f, MAXNRM/nrm);
      float Shn=scl*scl*n2h;
      float nh2=sqrtf(Shn+EPSF);
      float slh=atanhf(fminf(nh2,MAXNRM))/nh2;
      coefB_s[0]=scl*q1; coefB_s[1]=scl*q2*sld;
      coefB_s[2]=g0; coefB_s[3]=g1; coefB_s[4]=g2; coefB_s[5]=g3;
      coefB_s[6]=slh;
      Sh=Shn;
    }
    __syncthreads();

    // ---- P8: h update + write Xout (threads 0..511) ----
    if(tid<Hh){
      float cz1=coefA_s[3], cz2=coefA_s[4], cz3=coefA_s[5];
      float qc1=coefB_s[0], qc2=coefB_s[1];
      float g0=coefB_s[2], g1=coefB_s[3], g2=coefB_s[4], g3=coefB_s[5];
      float slh=coefB_s[6];
      float z  = sigm(cz1*mz_s[tid] + cz2*XZ[row+tid] + cz3*bias1[tid]);
      float dl = g0*h_s[tid] + g1*mh_s[tid] + g2*XH[row+tid] + g3*bias2[tid];
      float hn = qc1*h_s[tid] + qc2*z*dl;
      h_s[tid]=hn; lh_s[tid]=slh*hn;
      Xout[row+tid]=hn;
    }
    __syncthreads();
  }
}

// ---------------- fused MLR + online softmax partials ----------------
__global__ __launch_bounds__(256) void k_mlr(const float* __restrict__ X,
    const float* __restrict__ P, const float* __restrict__ A,
    const float* __restrict__ pp, const float* __restrict__ aa, const float* __restrict__ pa,
    const int* __restrict__ tgt, float* __restrict__ pm, float* __restrict__ tl){
  constexpr int RT = 32;
  int split = blockIdx.x;      // 0..7
  int rg = blockIdx.y;         // 0..63
  int rbase = rg*RT;
  __shared__ float Xs[RT][516];
  __shared__ float par[8][RT];
  __shared__ float ms[8][RT][2];
  __shared__ float xxs[RT];
  int tid = threadIdx.x;
  #pragma unroll
  for(int u=0;u<16;u++){
    int fi = u*256 + tid;
    int row = fi >> 7, c4 = fi & 127;
    float4 v = ld4(X + (size_t)(rbase+row)*Hh + c4*4);
    st4(&Xs[row][c4*4], v);
  }
  __syncthreads();
  { int r = tid & 31, seg = tid >> 5;
    float s = 0;
    for(int k=seg*64;k<seg*64+64;k++){ float x = Xs[r][k]; s += x*x; }
    par[seg][r] = s; }
  __syncthreads();
  if(tid < RT){ float s=0; for(int i=0;i<8;i++) s += par[i][tid]; xxs[tid]=s; }
  __syncthreads();
  int r = tid & 31, vi = tid >> 5;
  int rr = rbase + r;
  int tt = rr >> 4, bbr2 = rr & 15;
  int tok = tgt[bbr2*Ss + tt];
  float xx = xxs[r];
  float m = -3.0e38f, sacc = 0.f;
  int v0 = split*1250, v1e = v0 + 1250;
  const float4* Xrow = (const float4*)&Xs[r][0];
  for(int vbv=v0; vbv<v1e; vbv+=8){
    int v = vbv + vi;
    if(v < v1e){
      float px=0, xa=0;
      const float4* Pr = (const float4*)(P + (size_t)v*Hh);
      const float4* Ar = (const float4*)(A + (size_t)v*Hh);
      #pragma unroll 4
      for(int k4=0;k4<128;k4++){
        float4 xv = Xrow[k4];
        float4 pvv = Pr[k4]; float4 av = Ar[k4];
        px += dot4(xv,pvv); xa += dot4(xv,av);
      }
      float ppv = pp[v], aav = aa[v], pav = pa[v];
      float al = 1.f - 2.f*px + xx;
      float be = 1.f - ppv;
      float gm = 1.f - 2.f*px + ppv*xx;
      float da = (-al*pav + be*xa)/gm;
      float dd = (al*al*ppv - 2.f*al*be*px + be*be*xx)/(gm*gm);
      float lam = 2.f/(1.f - ppv);
      float arg = 2.f*da/((1.f - dd)*aav + EPSF);
      float lg = lam*aav*asinhf(arg);
      if(v == tok) tl[rr] = lg;
      if(lg > m){ sacc = sacc*expf(m - lg) + 1.f; m = lg; }
      else sacc += expf(lg - m);
    }
  }
  ms[vi][r][0] = m; ms[vi][r][1] = sacc;
  __syncthreads();
  if(vi==0){
    float M = -3.0e38f;
    for(int i=0;i<8;i++) M = fmaxf(M, ms[i][r][0]);
    float Ssum = 0.f;
    for(int i=0;i<8;i++) Ssum += ms[i][r][1]*expf(ms[i][r][0]-M);
    pm[((size_t)rr*8 + split)*2 + 0] = M;
    pm[((size_t)rr*8 + split)*2 + 1] = Ssum;
  }
}

// ---------------- final merge + mean NLL ----------------
__global__ void k_final(const float* __restrict__ pm, const float* __restrict__ tl, float* __restrict__ out){
  int tid = threadIdx.x;
  __shared__ float sred[4];
  float acc = 0.f;
  for(int q=0;q<8;q++){
    int rr = q*256 + tid;
    float M = -3.0e38f;
    for(int s=0;s<8;s++) M = fmaxf(M, pm[((size_t)rr*8+s)*2]);
    float Ssum = 0.f;
    for(int s=0;s<8;s++) Ssum += pm[((size_t)rr*8+s)*2+1]*expf(pm[((size_t)rr*8+s)*2]-M);
    acc += (M + logf(Ssum)) - tl[rr];
  }
  for(int o=32;o;o>>=1) acc += __shfl_down(acc,o);
  if((tid&63)==0) sred[tid>>6] = acc;
  __syncthreads();
  if(tid==0) out[0] = (sred[0]+sred[1]+sred[2]+sred[3]) / 2048.f;
}

extern "C" void kernel_launch(void* const* d_in, const int* in_sizes, int n_in,
                              void* d_out, int out_size, void* d_ws, size_t ws_size,
                              hipStream_t stream){
  const int* inp = (const int*)d_in[0];
  const int* tgt = (const int*)d_in[1];
  const float* E  = (const float*)d_in[2];
  const float* Wr = (const float*)d_in[3];
  const float* Wz = (const float*)d_in[4];
  const float* Wh = (const float*)d_in[5];
  const float* Ur = (const float*)d_in[6];
  const float* Uz = (const float*)d_in[7];
  const float* Uh = (const float*)d_in[8];
  const float* br = (const float*)d_in[9];
  const float* bz = (const float*)d_in[10];
  const float* bh = (const float*)d_in[11];
  const float* P  = (const float*)d_in[12];
  const float* A  = (const float*)d_in[13];
  float* out = (float*)d_out;
  float* w = (float*)d_ws;
  size_t o = 0;
  auto take = [&](size_t n){ float* p = w + o; o += n; return p; };
  float* Xa  = take((size_t)Nn*Hh);
  float* Xb  = take((size_t)Nn*Hh);
  float* LX  = take((size_t)Nn*Hh);
  float* XR  = take((size_t)Nn*Hh);
  float* XZ  = take((size_t)Nn*Hh);
  float* XH  = take((size_t)Nn*Hh);
  ushort* T2r = (ushort*)take((size_t)Ll*Hh*Hh/2);
  ushort* T2z = (ushort*)take((size_t)Ll*Hh*Hh/2);
  ushort* T2h = (ushort*)take((size_t)Ll*Hh*Hh/2);
  float* pubX = take((size_t)Nn*6);
  float* pp  = take(10240);
  float* aa  = take(10240);
  float* pa  = take(10240);
  float* pm  = take((size_t)Nn*8*2);
  float* tl  = take((size_t)Nn);
  if(ws_size < o*sizeof(float)) return;

  hipLaunchKernelGGL(k_transw, dim3(16,16,9), dim3(32,8), 0, stream, Wr,Wz,Wh, T2r,T2z,T2h);
  hipLaunchKernelGGL(k_pav, dim3(2500), dim3(256), 0, stream, P,A, pp,aa,pa);
  hipLaunchKernelGGL(k_embed, dim3(Nn), dim3(128), 0, stream, inp, E, Xa);
  float* cur = Xa; float* nxt = Xb;
  for(int l=0;l<Ll;l++){
    hipLaunchKernelGGL(k_logmap, dim3(Nn), dim3(128), 0, stream, cur, LX);
    hipLaunchKernelGGL(k_gemm, dim3(24,32), dim3(256), 0, stream, LX,
                       Ur + (size_t)l*Hh*Hh, Uz + (size_t)l*Hh*Hh, Uh + (size_t)l*Hh*Hh,
                       XR, XZ, XH);
    hipLaunchKernelGGL(k_expmap, dim3(Nn,3), dim3(128), 0, stream, XR,XZ,XH);
    hipLaunchKernelGGL(k_predots, dim3(Nn), dim3(128), 0, stream, XR,XZ,XH,
                       br + l*Hh, bz + l*Hh, bh + l*Hh, pubX);
    hipLaunchKernelGGL(k_scan7, dim3(Bb), dim3(1024), 0, stream, XR,XZ,XH,
                       T2r + (size_t)l*Hh*Hh, T2z + (size_t)l*Hh*Hh, T2h + (size_t)l*Hh*Hh,
                       br + l*Hh, bz + l*Hh, bh + l*Hh, pubX, nxt);
    float* tmp = cur; cur = nxt; nxt = tmp;
  }
  hipLaunchKernelGGL(k_mlr, dim3(8,64), dim3(256), 0, stream, cur, P, A, pp,aa,pa, tgt, pm, tl);
  hipLaunchKernelGGL(k_final, dim3(1), dim3(256), 0, stream, pm, tl, out);
}

// Round 8
// 8843.380 us; speedup vs baseline: 2.5787x; 1.2376x over previous
//
#include <hip/hip_runtime.h>
#include <hip/hip_bf16.h>
#include <math.h>

#define EPSF 1e-7f
#define MAXNRM 0.99999f

static constexpr int Bb = 16, Ss = 128, Hh = 512, Vv = 10000, Ll = 3;
static constexpr int Nn = Bb * Ss; // 2048
static constexpr int VT = 625;     // vocab tiles of 16

typedef __attribute__((ext_vector_type(4))) float f32x4;
typedef __attribute__((ext_vector_type(8))) short short8v;
typedef _Float16 h2 __attribute__((ext_vector_type(2)));

__device__ inline float4 ld4(const float* p){ return *(const float4*)p; }
__device__ inline void st4(float* p, float4 v){ *(float4*)p = v; }
__device__ inline float dot4(float4 a, float4 b){ return a.x*b.x + a.y*b.y + a.z*b.z + a.w*b.w; }
__device__ inline float sigm(float x){ return 1.f/(1.f + expf(-x)); }
__device__ inline unsigned short f2bf(float f){
  __hip_bfloat16 h = __float2bfloat16(f);
  return __builtin_bit_cast(unsigned short, h);
}
__device__ inline unsigned short f2h(float f){
  _Float16 h = (_Float16)f;
  return __builtin_bit_cast(unsigned short, h);
}
__device__ inline float rsum64f(float v){
  v+=__shfl_xor(v,32); v+=__shfl_xor(v,16); v+=__shfl_xor(v,8);
  v+=__shfl_xor(v,4);  v+=__shfl_xor(v,2);  v+=__shfl_xor(v,1); return v;
}

// ---------------- pack W[l][j][k] -> f16 k-pair-packed Wt: W2[lm][kp][j] ----------------
// W2[kp][j] = uint( f16 W[j][2kp] | f16 W[j][2kp+1] << 16 )
__global__ __launch_bounds__(256) void k_packW16(const float* __restrict__ Wr,
    const float* __restrict__ Wz, const float* __restrict__ Wh, uint* __restrict__ W2){
  int jt = blockIdx.x, kt2 = blockIdx.y, lm = blockIdx.z;
  int l = lm/3, m = lm%3;
  const float* src = (m==0?Wr: m==1?Wz: Wh) + (size_t)l*Hh*Hh;
  uint* dst = W2 + (size_t)lm*(256*Hh);
  __shared__ float t[64][65];
  int tid = threadIdx.x;
  #pragma unroll
  for(int p=0;p<4;p++){
    int row = p*16 + (tid>>4);
    int c4 = (tid&15)*4;
    st4(&t[row][c4], ld4(src + ((size_t)(jt*64+row))*Hh + kt2*64 + c4));
  }
  __syncthreads();
  int kp_l = tid >> 3;
  int j8 = (tid & 7)*8;
  uint u[8];
  #pragma unroll
  for(int i=0;i<8;i++){
    int jl = j8 + i;
    u[i] = (uint)f2h(t[jl][2*kp_l]) | ((uint)f2h(t[jl][2*kp_l+1]) << 16);
  }
  uint* o = dst + (size_t)(kt2*32 + kp_l)*Hh + jt*64 + j8;
  *(uint4*)(o)   = make_uint4(u[0],u[1],u[2],u[3]);
  *(uint4*)(o+4) = make_uint4(u[4],u[5],u[6],u[7]);
}

// ---------------- pack 16 rows of a [*,512] f32 matrix into bf16 MFMA fragments ----------------
// dst[(vt*16+kt)*64+lane][8]: elem = src[vt*16 + (lane&15)][kt*32 + (lane>>4)*8 + i]
__global__ __launch_bounds__(256) void k_packF(const float* __restrict__ src, ushort* __restrict__ dst){
  int vt = blockIdx.x;
  __shared__ float rows[16][516];
  int tid = threadIdx.x;
  #pragma unroll
  for(int p=0;p<8;p++){
    int idx = p*256 + tid;
    int row = idx >> 7, c4 = idx & 127;
    st4(&rows[row][c4*4], ld4(src + ((size_t)vt*16+row)*Hh + c4*4));
  }
  __syncthreads();
  #pragma unroll
  for(int p=0;p<4;p++){
    int idx = p*256 + tid;
    int kt = idx >> 6, lane = idx & 63;
    int vloc = lane & 15, k0 = kt*32 + ((lane>>4)&3)*8;
    union { ushort u[8]; uint4 v; } tt;
    #pragma unroll
    for(int i=0;i<8;i++) tt.u[i] = f2bf(rows[vloc][k0+i]);
    *(uint4*)(dst + (((size_t)vt*16 + kt)*64 + lane)*8) = tt.v;
  }
}

// ---------------- per-(t,b) input-only dots ----------------
__global__ void k_predots(const float* __restrict__ XR, const float* __restrict__ XZ,
                          const float* __restrict__ XH,
                          const float* __restrict__ br, const float* __restrict__ bz,
                          const float* __restrict__ bh, float* __restrict__ pubX){
  int n = blockIdx.x; int tid = threadIdx.x; // 128 threads
  float s0=0,s1=0,s2=0,s3=0,s4=0,s5=0;
  for(int i=tid;i<Hh;i+=128){
    float xr=XR[(size_t)n*Hh+i], xz=XZ[(size_t)n*Hh+i], xh=XH[(size_t)n*Hh+i];
    s0+=xr*xr; s1+=xr*br[i]; s2+=xz*xz; s3+=xz*bz[i]; s4+=xh*xh; s5+=xh*bh[i];
  }
  __shared__ float red[2][6];
  s0=rsum64f(s0); s1=rsum64f(s1); s2=rsum64f(s2);
  s3=rsum64f(s3); s4=rsum64f(s4); s5=rsum64f(s5);
  int w = tid>>6;
  if((tid&63)==0){ red[w][0]=s0; red[w][1]=s1; red[w][2]=s2; red[w][3]=s3; red[w][4]=s4; red[w][5]=s5; }
  __syncthreads();
  if(tid==0){
    #pragma unroll
    for(int d=0;d<6;d++) pubX[(size_t)n*6+d] = red[0][d]+red[1][d];
  }
}

// ---------------- per-vocab constants ----------------
__global__ void k_pav(const float* __restrict__ P, const float* __restrict__ A,
                      float* __restrict__ pp, float* __restrict__ aa, float* __restrict__ pa){
  int w = threadIdx.x >> 6, lane = threadIdx.x & 63;
  int v = blockIdx.x*4 + w;
  const float4* Pr = (const float4*)(P + (size_t)v*Hh);
  const float4* Ar = (const float4*)(A + (size_t)v*Hh);
  float sp=0, sa=0, spa=0;
  #pragma unroll
  for(int i=0;i<2;i++){
    int k4 = lane*2 + i;
    float4 pv = Pr[k4], av = Ar[k4];
    sp += dot4(pv,pv); sa += dot4(av,av); spa += dot4(pv,av);
  }
  for(int o=32;o;o>>=1){ sp+=__shfl_down(sp,o); sa+=__shfl_down(sa,o); spa+=__shfl_down(spa,o); }
  if(lane==0){ pp[v]=sp; aa[v]=sqrtf(sa+EPSF); pa[v]=spa; }
}

// ---------------- embedding gather ----------------
__global__ void k_embed(const int* __restrict__ inp, const float* __restrict__ E, float* __restrict__ X){
  int n = blockIdx.x; int t = n >> 4, b = n & 15;
  int tok = inp[b*Ss + t];
  int i = threadIdx.x;
  st4(X + (size_t)n*Hh + i*4, ld4(E + (size_t)tok*Hh + i*4));
}

// ---------------- row logmap0 ----------------
__global__ void k_logmap(const float* __restrict__ X, float* __restrict__ LX){
  int n = blockIdx.x; int t = threadIdx.x;
  __shared__ float sred[2];
  float4 v = ld4(X + (size_t)n*Hh + t*4);
  float ss = dot4(v,v);
  for(int o=32;o;o>>=1) ss += __shfl_down(ss,o);
  if((t&63)==0) sred[t>>6] = ss;
  __syncthreads();
  ss = sred[0]+sred[1];
  float nn = sqrtf(ss + EPSF);
  float sc = atanhf(fminf(nn, MAXNRM)) / nn;
  v.x*=sc; v.y*=sc; v.z*=sc; v.w*=sc;
  st4(LX + (size_t)n*Hh + t*4, v);
}

// ---------------- row expmap0 (in place, 3 buffers) ----------------
__global__ void k_expmap(float* __restrict__ XR, float* __restrict__ XZ, float* __restrict__ XH){
  float* Xp = blockIdx.y==0 ? XR : (blockIdx.y==1 ? XZ : XH);
  int n = blockIdx.x; int t = threadIdx.x;
  __shared__ float sred[2];
  float4 v = ld4(Xp + (size_t)n*Hh + t*4);
  float ss = dot4(v,v);
  for(int o=32;o;o>>=1) ss += __shfl_down(ss,o);
  if((t&63)==0) sred[t>>6] = ss;
  __syncthreads();
  ss = sred[0]+sred[1];
  float nn = sqrtf(ss + EPSF);
  float sc = tanhf(nn) / nn;
  v.x*=sc; v.y*=sc; v.z*=sc; v.w*=sc;
  st4(Xp + (size_t)n*Hh + t*4, v);
}

// ---------------- GEMM: LX[2048,512] @ {Ur|Uz|Uh}^T ----------------
__global__ __launch_bounds__(256) void k_gemm(const float* __restrict__ A4,
    const float* __restrict__ U0, const float* __restrict__ U1, const float* __restrict__ U2,
    float* __restrict__ O0, float* __restrict__ O1, float* __restrict__ O2){
  __shared__ float As[16][65], Bs[16][65];
  int jb = blockIdx.x;
  int nb = blockIdx.y;
  int mat = jb >> 3; int j0 = (jb & 7)*64;
  const float* Bm = mat==0?U0 : (mat==1?U1:U2);
  float* Om       = mat==0?O0 : (mat==1?O1:O2);
  int tid = threadIdx.x;
  int lr = tid >> 2, lq = tid & 3;
  int tx = tid & 15, ty = tid >> 4;
  float acc[4][4] = {};
  for(int kb=0; kb<Hh; kb+=16){
    float4 av = ld4(A4 + (size_t)(nb*64+lr)*Hh + kb + lq*4);
    float4 bv = ld4(Bm + (size_t)(j0+lr)*Hh + kb + lq*4);
    As[lq*4+0][lr]=av.x; As[lq*4+1][lr]=av.y; As[lq*4+2][lr]=av.z; As[lq*4+3][lr]=av.w;
    Bs[lq*4+0][lr]=bv.x; Bs[lq*4+1][lr]=bv.y; Bs[lq*4+2][lr]=bv.z; Bs[lq*4+3][lr]=bv.w;
    __syncthreads();
    #pragma unroll
    for(int kk=0;kk<16;kk++){
      float a0=As[kk][ty*4+0], a1=As[kk][ty*4+1], a2=As[kk][ty*4+2], a3=As[kk][ty*4+3];
      float b0=Bs[kk][tx*4+0], b1=Bs[kk][tx*4+1], b2=Bs[kk][tx*4+2], b3=Bs[kk][tx*4+3];
      acc[0][0]+=a0*b0; acc[0][1]+=a0*b1; acc[0][2]+=a0*b2; acc[0][3]+=a0*b3;
      acc[1][0]+=a1*b0; acc[1][1]+=a1*b1; acc[1][2]+=a1*b2; acc[1][3]+=a1*b3;
      acc[2][0]+=a2*b0; acc[2][1]+=a2*b1; acc[2][2]+=a2*b2; acc[2][3]+=a2*b3;
      acc[3][0]+=a3*b0; acc[3][1]+=a3*b1; acc[3][2]+=a3*b2; acc[3][3]+=a3*b3;
    }
    __syncthreads();
  }
  for(int i=0;i<4;i++)
    for(int j2=0;j2<4;j2++)
      Om[(size_t)(nb*64+ty*4+i)*Hh + j0 + tx*4 + j2] = acc[i][j2];
}

// ---------------- independent per-batch-row GRU scan, f16 pair-packed dot2 streaming ----------------
__global__ __launch_bounds__(1024) void k_scan8(
    const float* __restrict__ XR, const float* __restrict__ XZ, const float* __restrict__ XH,
    const uint* __restrict__ W2r, const uint* __restrict__ W2z, const uint* __restrict__ W2h,
    const float* __restrict__ br, const float* __restrict__ bz, const float* __restrict__ bh,
    const float* __restrict__ pubX, float* __restrict__ Xout){
  const int b = blockIdx.x;
  const int tid = threadIdx.x;
  const int lane = tid & 63, wv = tid >> 6;   // 16 waves

  __shared__ float part[16][Hh];
  __shared__ float mr_s[Hh], mz_s[Hh], mh_s[Hh];
  __shared__ float h_s[Hh], lh_s[Hh];
  __shared__ uint  lh2_s[256], ap2_s[256];    // f16-pair packed
  __shared__ float bias0[Hh], bias1[Hh], bias2[Hh];
  __shared__ float partA[8][8];
  __shared__ float partB[8][18];
  __shared__ float coefA_s[8], coefB_s[8], bb_s[4];

  if(tid<Hh){ h_s[tid]=0.f; lh_s[tid]=0.f; }
  if(tid<256) lh2_s[tid]=0u;
  for(int i=tid;i<Hh;i+=1024){ bias0[i]=br[i]; bias1[i]=bz[i]; bias2[i]=bh[i]; }
  __syncthreads();
  {
    float p0=0,p1=0,p2=0;
    if(tid<Hh){ float a=bias0[tid],b2=bias1[tid],c2=bias2[tid]; p0=a*a; p1=b2*b2; p2=c2*c2; }
    p0=rsum64f(p0); p1=rsum64f(p1); p2=rsum64f(p2);
    if(tid<Hh && lane==0){ partB[wv][0]=p0; partB[wv][1]=p1; partB[wv][2]=p2; }
    __syncthreads();
    if(tid==0){
      float a=0,b2=0,c2=0;
      for(int i=0;i<8;i++){ a+=partB[i][0]; b2+=partB[i][1]; c2+=partB[i][2]; }
      bb_s[0]=a; bb_s[1]=b2; bb_s[2]=c2;
    }
    __syncthreads();
  }

  float Sh = 0.f, hxh = 0.f, hbh = 0.f;
  const int j8 = (tid & 63) * 8;

  for(int ts=0; ts<Ss; ts++){
    const size_t row = (size_t)(ts*Bb + b)*Hh;

    // ---- M1: mr (0..511) / mz (512..1023); 8-way k-split, f16 dot2 ----
    {
      int hf = tid >> 9;
      int kq = (tid >> 6) & 7;
      int kp0 = kq*32;
      const uint* W = (hf ? W2z : W2r) + (size_t)kp0*Hh + j8;
      f32x4 a0 = {0,0,0,0}, a1 = {0,0,0,0};
      #pragma unroll 8
      for(int kk=0; kk<32; kk++){
        uint4 wa = *(const uint4*)(W + (size_t)kk*Hh);
        uint4 wb = *(const uint4*)(W + (size_t)kk*Hh + 4);
        h2 lv = __builtin_bit_cast(h2, lh2_s[kp0+kk]);
        a0[0]=__builtin_amdgcn_fdot2(__builtin_bit_cast(h2,wa.x), lv, a0[0], false);
        a0[1]=__builtin_amdgcn_fdot2(__builtin_bit_cast(h2,wa.y), lv, a0[1], false);
        a0[2]=__builtin_amdgcn_fdot2(__builtin_bit_cast(h2,wa.z), lv, a0[2], false);
        a0[3]=__builtin_amdgcn_fdot2(__builtin_bit_cast(h2,wa.w), lv, a0[3], false);
        a1[0]=__builtin_amdgcn_fdot2(__builtin_bit_cast(h2,wb.x), lv, a1[0], false);
        a1[1]=__builtin_amdgcn_fdot2(__builtin_bit_cast(h2,wb.y), lv, a1[1], false);
        a1[2]=__builtin_amdgcn_fdot2(__builtin_bit_cast(h2,wb.z), lv, a1[2], false);
        a1[3]=__builtin_amdgcn_fdot2(__builtin_bit_cast(h2,wb.w), lv, a1[3], false);
      }
      float* d = &part[hf*8+kq][j8];
      *(f32x4*)d = a0; *(f32x4*)(d+4) = a1;
    }
    __syncthreads();
    {
      int j = tid & 511;
      if(tid < 512){
        float s=0;
        #pragma unroll
        for(int q=0;q<8;q++) s += part[q][j];
        mr_s[j]=s;
      } else {
        float s=0;
        #pragma unroll
        for(int q=8;q<16;q++) s += part[q][j];
        mz_s[j]=s;
      }
    }
    __syncthreads();

    // ---- A-dots (8) ----
    if(tid<Hh){
      float mr=mr_s[tid], mz=mz_s[tid], hv=h_s[tid];
      float xr=XR[row+tid], xz=XZ[row+tid], xh=XH[row+tid];
      float brc=bias0[tid], bzc=bias1[tid], bhc=bias2[tid];
      float p0=mr*mr, p1=mr*xr, p2=mr*brc, p3=mz*mz, p4=mz*xz, p5=mz*bzc, p6=hv*xh, p7=hv*bhc;
      p0=rsum64f(p0); p1=rsum64f(p1); p2=rsum64f(p2); p3=rsum64f(p3);
      p4=rsum64f(p4); p5=rsum64f(p5); p6=rsum64f(p6); p7=rsum64f(p7);
      if(lane==0){
        partA[wv][0]=p0; partA[wv][1]=p1; partA[wv][2]=p2; partA[wv][3]=p3;
        partA[wv][4]=p4; partA[wv][5]=p5; partA[wv][6]=p6; partA[wv][7]=p7;
      }
    }
    __syncthreads();

    // ---- gate coefficients (thread 0) ----
    if(tid==0){
      float s[8];
      #pragma unroll
      for(int d=0;d<8;d++){
        float x=0;
        for(int i=0;i<8;i++) x+=partA[i][d];
        s[d]=x;
      }
      hxh=s[6]; hbh=s[7];
      const float* px = pubX + (size_t)(ts*Bb+b)*6;
      float xrxr=px[0], xrbr=px[1], xzxz=px[2], xzbz=px[3];
      float bbr=bb_s[0], bbz=bb_s[1];
      float nm=sqrtf(s[0]+EPSF), se=tanhf(nm)/nm;
      float uv=se*s[1], uu=se*se*s[0], vvr=xrxr;
      float den=1.f+2.f*uv+uu*vvr;
      float a1=(1.f+2.f*uv+vvr)*se/den, a2=(1.f-uu)/den;
      float uv2=a1*s[2]+a2*xrbr;
      float uu2=a1*a1*s[0]+2.f*a1*a2*s[1]+a2*a2*xrxr;
      float den2=1.f+2.f*uv2+uu2*bbr;
      float b1=(1.f+2.f*uv2+bbr)/den2, b2c=(1.f-uu2)/den2;
      float c1=b1*a1, c2=b1*a2, c3=b2c;
      float n2sq=c1*c1*s[0]+c2*c2*xrxr+c3*c3*bbr+2.f*(c1*c2*s[1]+c1*c3*s[2]+c2*c3*xrbr);
      float nn2=sqrtf(n2sq+EPSF);
      float s_r=atanhf(fminf(nn2,MAXNRM))/nn2;
      coefA_s[0]=s_r*c1; coefA_s[1]=s_r*c2; coefA_s[2]=s_r*c3;
      float nmz=sqrtf(s[3]+EPSF), sez=tanhf(nmz)/nmz;
      float uvz=sez*s[4], uuz=sez*sez*s[3], vvz=xzxz;
      float denz=1.f+2.f*uvz+uuz*vvz;
      float az1=(1.f+2.f*uvz+vvz)*sez/denz, az2=(1.f-uuz)/denz;
      float uvz2=az1*s[5]+az2*xzbz;
      float uuz2=az1*az1*s[3]+2.f*az1*az2*s[4]+az2*az2*xzxz;
      float denz2=1.f+2.f*uvz2+uuz2*bbz;
      float bz1=(1.f+2.f*uvz2+bbz)/denz2, bz2=(1.f-uuz2)/denz2;
      float cz1=bz1*az1, cz2=bz1*az2, cz3=bz2;
      float nz2sq=cz1*cz1*s[3]+cz2*cz2*xzxz+cz3*cz3*bbz+2.f*(cz1*cz2*s[4]+cz1*cz3*s[5]+cz2*cz3*xzbz);
      float nnz2=sqrtf(nz2sq+EPSF);
      float s_z=atanhf(fminf(nnz2,MAXNRM))/nnz2;
      coefA_s[3]=s_z*cz1; coefA_s[4]=s_z*cz2; coefA_s[5]=s_z*cz3;
    }
    __syncthreads();

    // ---- ap = r .* lh, f16-pair packed (threads 0..255, 2 elems each) ----
    if(tid<256){
      int e0 = tid*2;
      float ca=coefA_s[0], cb=coefA_s[1], cc2=coefA_s[2];
      float r0 = sigm(ca*mr_s[e0]   + cb*XR[row+e0]   + cc2*bias0[e0]);
      float r1 = sigm(ca*mr_s[e0+1] + cb*XR[row+e0+1] + cc2*bias0[e0+1]);
      float ap0 = r0*lh_s[e0], ap1 = r1*lh_s[e0+1];
      ap2_s[tid] = (uint)f2h(ap0) | ((uint)f2h(ap1)<<16);
    }
    __syncthreads();

    // ---- M2: mh, 16-way k-split, f16 dot2 ----
    {
      int ks = tid >> 6;
      int kp0 = ks*16;
      const uint* W = W2h + (size_t)kp0*Hh + j8;
      f32x4 a0 = {0,0,0,0}, a1 = {0,0,0,0};
      #pragma unroll 8
      for(int kk=0; kk<16; kk++){
        uint4 wa = *(const uint4*)(W + (size_t)kk*Hh);
        uint4 wb = *(const uint4*)(W + (size_t)kk*Hh + 4);
        h2 lv = __builtin_bit_cast(h2, ap2_s[kp0+kk]);
        a0[0]=__builtin_amdgcn_fdot2(__builtin_bit_cast(h2,wa.x), lv, a0[0], false);
        a0[1]=__builtin_amdgcn_fdot2(__builtin_bit_cast(h2,wa.y), lv, a0[1], false);
        a0[2]=__builtin_amdgcn_fdot2(__builtin_bit_cast(h2,wa.z), lv, a0[2], false);
        a0[3]=__builtin_amdgcn_fdot2(__builtin_bit_cast(h2,wa.w), lv, a0[3], false);
        a1[0]=__builtin_amdgcn_fdot2(__builtin_bit_cast(h2,wb.x), lv, a1[0], false);
        a1[1]=__builtin_amdgcn_fdot2(__builtin_bit_cast(h2,wb.y), lv, a1[1], false);
        a1[2]=__builtin_amdgcn_fdot2(__builtin_bit_cast(h2,wb.z), lv, a1[2], false);
        a1[3]=__builtin_amdgcn_fdot2(__builtin_bit_cast(h2,wb.w), lv, a1[3], false);
      }
      float* d = &part[ks][j8];
      *(f32x4*)d = a0; *(f32x4*)(d+4) = a1;
    }
    __syncthreads();
    if(tid<Hh){
      float s=0;
      #pragma unroll
      for(int q=0;q<16;q++) s += part[q][tid];
      mh_s[tid]=s;
    }
    __syncthreads();

    // ---- B-dots (18) ----
    if(tid<Hh){
      float mh=mh_s[tid], mz=mz_s[tid], hv=h_s[tid];
      float xh=XH[row+tid], xz=XZ[row+tid];
      float bhc=bias2[tid], bzc=bias1[tid];
      float z = sigm(coefA_s[3]*mz + coefA_s[4]*xz + coefA_s[5]*bzc);
      float eh=z*hv, em=z*mh, ex=z*xh, eb=z*bhc;
      float p[18] = {mh*mh, mh*xh, mh*bhc, hv*mh,
                     eh*eh, eh*em, eh*ex, eh*eb,
                     em*em, em*ex, em*eb, ex*ex, ex*eb, eb*eb,
                     hv*eh, hv*em, hv*ex, hv*eb};
      #pragma unroll
      for(int d=0;d<18;d++) p[d]=rsum64f(p[d]);
      if(lane==0){
        #pragma unroll
        for(int d=0;d<18;d++) partB[wv][d]=p[d];
      }
    }
    __syncthreads();

    // ---- update coefficients (thread 0) ----
    if(tid==0){
      float dsum[18];
      #pragma unroll
      for(int d=0;d<18;d++){
        float x=0;
        for(int i=0;i<8;i++) x+=partB[i][d];
        dsum[d]=x;
      }
      float d0=dsum[0], d1=dsum[1], d2=dsum[2], d3=dsum[3];
      float Ghh=dsum[4], Ghm=dsum[5], Ghx=dsum[6], Ghb=dsum[7];
      float Gmm=dsum[8], Gmx=dsum[9], Gmb=dsum[10];
      float Gxx=dsum[11], Gxb=dsum[12], Gbb=dsum[13];
      float Heh=dsum[14], Hem=dsum[15], Hex=dsum[16], Heb=dsum[17];
      const float* px = pubX + (size_t)(ts*Bb+b)*6;
      float xhxh=px[4], xhbh=px[5];
      float bbh=bb_s[2]; float Shb=Sh;
      float nm3=sqrtf(d0+EPSF), se3=tanhf(nm3)/nm3;
      float uvh=se3*d1, uuh=se3*se3*d0, vvh=xhxh;
      float denh=1.f+2.f*uvh+uuh*vvh;
      float a1p=(1.f+2.f*uvh+vvh)*se3/denh, a2p=(1.f-uuh)/denh;
      float uv2h=a1p*d2+a2p*xhbh;
      float uu2h=a1p*a1p*d0+2.f*a1p*a2p*d1+a2p*a2p*xhxh;
      float den2h=1.f+2.f*uv2h+uu2h*bbh;
      float b1p=(1.f+2.f*uv2h+bbh)/den2h, b2p=(1.f-uu2h)/den2h;
      float c1p=b1p*a1p, c2p=b1p*a2p, c3p=b2p;
      float h_htil=c1p*d3+c2p*hxh+c3p*hbh;
      float htil2=c1p*c1p*d0+c2p*c2p*xhxh+c3p*c3p*bbh
                +2.f*(c1p*c2p*d1+c1p*c3p*d2+c2p*c3p*xhbh);
      float denD=1.f-2.f*h_htil+Shb*htil2;
      float dd1=(1.f-2.f*h_htil+htil2)/denD, dd2=(1.f-Shb)/denD;
      float g0=-dd1, g1=dd2*c1p, g2=dd2*c2p, g3=dd2*c3p;
      float del2=g0*g0*Shb+g1*g1*d0+g2*g2*xhxh+g3*g3*bbh
               +2.f*(g0*g1*d3+g0*g2*hxh+g0*g3*hbh+g1*g2*d1+g1*g3*d2+g2*g3*xhbh);
      float ndl=sqrtf(del2+EPSF);
      float sld=atanhf(fminf(ndl,MAXNRM))/ndl;
      float Qe=g0*g0*Ghh+g1*g1*Gmm+g2*g2*Gxx+g3*g3*Gbb
             +2.f*(g0*g1*Ghm+g0*g2*Ghx+g0*g3*Ghb+g1*g2*Gmx+g1*g3*Gmb+g2*g3*Gxb);
      float Le=g0*Heh+g1*Hem+g2*Hex+g3*Heb;
      float Sww=sld*sld*Qe;
      float Shw=sld*Le;
      float nw=sqrtf(Sww+EPSF), sew=tanhf(nw)/nw;
      float uvw=sew*Shw, uuw=Shb, vvw=sew*sew*Sww;
      float denw=1.f+2.f*uvw+uuw*vvw;
      float p1=(1.f+2.f*uvw+vvw)/denw, p2=(1.f-uuw)/denw;
      float q1=p1, q2=p2*sew;
      float n2h=q1*q1*Shb+2.f*q1*q2*Shw+q2*q2*Sww;
      float nrm=sqrtf(n2h+EPSF);
      float scl=fminf(1.f, MAXNRM/nrm);
      float Shn=scl*scl*n2h;
      float nh2=sqrtf(Shn+EPSF);
      float slh=atanhf(fminf(nh2,MAXNRM))/nh2;
      coefB_s[0]=scl*q1; coefB_s[1]=scl*q2*sld;
      coefB_s[2]=g0; coefB_s[3]=g1; coefB_s[4]=g2; coefB_s[5]=g3;
      coefB_s[6]=slh;
      Sh=Shn;
    }
    __syncthreads();

    // ---- h update + write Xout + lh f16-pair (threads 0..255, 2 elems) ----
    if(tid<256){
      int e0 = tid*2;
      float cz1=coefA_s[3], cz2=coefA_s[4], cz3=coefA_s[5];
      float qc1=coefB_s[0], qc2=coefB_s[1];
      float g0=coefB_s[2], g1=coefB_s[3], g2=coefB_s[4], g3=coefB_s[5];
      float slh=coefB_s[6];
      float lh01[2];
      #pragma unroll
      for(int i=0;i<2;i++){
        int e = e0+i;
        float z  = sigm(cz1*mz_s[e] + cz2*XZ[row+e] + cz3*bias1[e]);
        float dl = g0*h_s[e] + g1*mh_s[e] + g2*XH[row+e] + g3*bias2[e];
        float hn = qc1*h_s[e] + qc2*z*dl;
        float lh = slh*hn;
        h_s[e]=hn; lh_s[e]=lh; lh01[i]=lh;
        Xout[row+e]=hn;
      }
      lh2_s[tid] = (uint)f2h(lh01[0]) | ((uint)f2h(lh01[1])<<16);
    }
    __syncthreads();
  }
}

// ---------------- MFMA MLR + online softmax partials ----------------
// grid (32 rowblocks of 64, 8 splits) x 256 thr (4 waves). 32 partials per row.
__global__ __launch_bounds__(256) void k_mlr2(
    const ushort* __restrict__ Xf, const ushort* __restrict__ Pf, const ushort* __restrict__ Af,
    const float* __restrict__ X, const float* __restrict__ pp, const float* __restrict__ aa,
    const float* __restrict__ pa, const int* __restrict__ tgt,
    float* __restrict__ pm, float* __restrict__ tl){
  int rb = blockIdx.x;
  int sp = blockIdx.y;
  int tid = threadIdx.x, lane = tid&63, w = tid>>6;
  __shared__ ushort Axf[4*16*64*8];   // 64KB: 4 rtiles of A-frags
  __shared__ float xxp[64][4];
  __shared__ float xxs[64];
  #pragma unroll
  for(int p=0;p<16;p++){
    int idx = p*256 + tid;
    ((uint4*)Axf)[idx] = ((const uint4*)Xf)[(size_t)rb*4096 + idx];
  }
  {
    int row = tid>>2, seg = tid&3;
    const float* xr = X + ((size_t)rb*64 + row)*Hh + seg*128;
    float s=0;
    #pragma unroll
    for(int i=0;i<32;i++){ float4 v4 = ld4(xr+i*4); s += dot4(v4,v4); }
    xxp[row][seg]=s;
  }
  __syncthreads();
  if(tid<64) xxs[tid] = xxp[tid][0]+xxp[tid][1]+xxp[tid][2]+xxp[tid][3];
  __syncthreads();

  float mM[16], sS[16]; int tokv[16];
  #pragma unroll
  for(int rt=0;rt<4;rt++)
    #pragma unroll
    for(int i=0;i<4;i++){
      int idx=rt*4+i;
      int rr = rb*64 + rt*16 + (lane>>4)*4 + i;
      tokv[idx] = tgt[(rr&15)*Ss + (rr>>4)];
      mM[idx] = -3.0e38f; sS[idx]=0.f;
    }

  for(int vt = sp*4 + w; vt < VT; vt += 32){
    int v = vt*16 + (lane&15);
    float ppv = pp[v], aav = aa[v], pav = pa[v];
    f32x4 aP[4], aA[4];
    #pragma unroll
    for(int rt=0;rt<4;rt++){ aP[rt]=(f32x4){0,0,0,0}; aA[rt]=(f32x4){0,0,0,0}; }
    const short8v* Pb = (const short8v*)(Pf + (size_t)vt*8192);
    const short8v* Ab = (const short8v*)(Af + (size_t)vt*8192);
    #pragma unroll
    for(int kt=0;kt<16;kt++){
      short8v bP = Pb[kt*64+lane];
      short8v bA = Ab[kt*64+lane];
      #pragma unroll
      for(int rt=0;rt<4;rt++){
        short8v a = *(const short8v*)&Axf[(((size_t)rt*16+kt)*64+lane)*8];
        aP[rt] = __builtin_amdgcn_mfma_f32_16x16x32_bf16(a, bP, aP[rt], 0,0,0);
        aA[rt] = __builtin_amdgcn_mfma_f32_16x16x32_bf16(a, bA, aA[rt], 0,0,0);
      }
    }
    float be = 1.f - ppv;
    float lamaa = (2.f/be)*aav;
    #pragma unroll
    for(int rt=0;rt<4;rt++)
      #pragma unroll
      for(int i=0;i<4;i++){
        int idx = rt*4+i;
        int rl = rt*16 + (lane>>4)*4 + i;
        float px = aP[rt][i], xa = aA[rt][i];
        float xx = xxs[rl];
        float al = 1.f - 2.f*px + xx;
        float gm = 1.f - 2.f*px + ppv*xx;
        float da = (-al*pav + be*xa)/gm;
        float dd = (al*al*ppv - 2.f*al*be*px + be*be*xx)/(gm*gm);
        float arg = 2.f*da/((1.f-dd)*aav + EPSF);
        float lg = lamaa*asinhf(arg);
        if(v == tokv[idx]) tl[rb*64 + rl] = lg;
        if(lg > mM[idx]){ sS[idx] = sS[idx]*expf(mM[idx]-lg) + 1.f; mM[idx]=lg; }
        else sS[idx] += expf(lg - mM[idx]);
      }
  }
  // merge across the 16 column-lanes of each row group
  #pragma unroll
  for(int o=1;o<16;o<<=1){
    #pragma unroll
    for(int idx=0;idx<16;idx++){
      float m2 = __shfl_xor(mM[idx], o);
      float s2 = __shfl_xor(sS[idx], o);
      float M = fmaxf(mM[idx], m2);
      sS[idx] = sS[idx]*expf(mM[idx]-M) + s2*expf(m2-M);
      mM[idx] = M;
    }
  }
  if((lane&15)==0){
    #pragma unroll
    for(int rt=0;rt<4;rt++)
      #pragma unroll
      for(int i=0;i<4;i++){
        int idx=rt*4+i;
        int rr = rb*64 + rt*16 + (lane>>4)*4 + i;
        pm[((size_t)rr*32 + sp*4 + w)*2+0] = mM[idx];
        pm[((size_t)rr*32 + sp*4 + w)*2+1] = sS[idx];
      }
  }
}

// ---------------- final merge + mean NLL (32 partials/row) ----------------
__global__ void k_final(const float* __restrict__ pm, const float* __restrict__ tl, float* __restrict__ out){
  int tid = threadIdx.x;
  __shared__ float sred[4];
  float acc = 0.f;
  for(int q=0;q<8;q++){
    int rr = q*256 + tid;
    float M = -3.0e38f;
    for(int s=0;s<32;s++) M = fmaxf(M, pm[((size_t)rr*32+s)*2]);
    float Ssum = 0.f;
    for(int s=0;s<32;s++) Ssum += pm[((size_t)rr*32+s)*2+1]*expf(pm[((size_t)rr*32+s)*2]-M);
    acc += (M + logf(Ssum)) - tl[rr];
  }
  for(int o=32;o;o>>=1) acc += __shfl_down(acc,o);
  if((tid&63)==0) sred[tid>>6] = acc;
  __syncthreads();
  if(tid==0) out[0] = (sred[0]+sred[1]+sred[2]+sred[3]) / 2048.f;
}

extern "C" void kernel_launch(void* const* d_in, const int* in_sizes, int n_in,
                              void* d_out, int out_size, void* d_ws, size_t ws_size,
                              hipStream_t stream){
  const int* inp = (const int*)d_in[0];
  const int* tgt = (const int*)d_in[1];
  const float* E  = (const float*)d_in[2];
  const float* Wr = (const float*)d_in[3];
  const float* Wz = (const float*)d_in[4];
  const float* Wh = (const float*)d_in[5];
  const float* Ur = (const float*)d_in[6];
  const float* Uz = (const float*)d_in[7];
  const float* Uh = (const float*)d_in[8];
  const float* br = (const float*)d_in[9];
  const float* bz = (const float*)d_in[10];
  const float* bh = (const float*)d_in[11];
  const float* P  = (const float*)d_in[12];
  const float* A  = (const float*)d_in[13];
  float* out = (float*)d_out;
  float* w = (float*)d_ws;
  size_t o = 0;
  auto take = [&](size_t n){ float* p = w + o; o += n; return p; };
  float* Xa  = take((size_t)Nn*Hh);
  float* Xb  = take((size_t)Nn*Hh);
  float* LX  = take((size_t)Nn*Hh);     // | contiguous region LX..W2 reused for Pf/Af after scans
  float* XR  = take((size_t)Nn*Hh);
  float* XZ  = take((size_t)Nn*Hh);
  float* XH  = take((size_t)Nn*Hh);
  uint*  W2  = (uint*)take((size_t)9*256*Hh);   // f16-pair packed weights (1.18M)
  float* pubX = take((size_t)Nn*6);
  float* pp  = take(10240);
  float* aa  = take(10240);
  float* pa  = take(10240);
  float* pm  = take((size_t)Nn*32*2);
  float* tl  = take((size_t)Nn);
  if(ws_size < o*sizeof(float)) return;

  hipLaunchKernelGGL(k_packW16, dim3(8,8,9), dim3(256), 0, stream, Wr,Wz,Wh, W2);
  hipLaunchKernelGGL(k_pav, dim3(2500), dim3(256), 0, stream, P,A, pp,aa,pa);
  hipLaunchKernelGGL(k_embed, dim3(Nn), dim3(128), 0, stream, inp, E, Xa);
  float* cur = Xa; float* nxt = Xb;
  for(int l=0;l<Ll;l++){
    hipLaunchKernelGGL(k_logmap, dim3(Nn), dim3(128), 0, stream, cur, LX);
    hipLaunchKernelGGL(k_gemm, dim3(24,32), dim3(256), 0, stream, LX,
                       Ur + (size_t)l*Hh*Hh, Uz + (size_t)l*Hh*Hh, Uh + (size_t)l*Hh*Hh,
                       XR, XZ, XH);
    hipLaunchKernelGGL(k_expmap, dim3(Nn,3), dim3(128), 0, stream, XR,XZ,XH);
    hipLaunchKernelGGL(k_predots, dim3(Nn), dim3(128), 0, stream, XR,XZ,XH,
                       br + l*Hh, bz + l*Hh, bh + l*Hh, pubX);
    hipLaunchKernelGGL(k_scan8, dim3(Bb), dim3(1024), 0, stream, XR,XZ,XH,
                       W2 + (size_t)(l*3+0)*256*Hh, W2 + (size_t)(l*3+1)*256*Hh,
                       W2 + (size_t)(l*3+2)*256*Hh,
                       br + l*Hh, bz + l*Hh, bh + l*Hh, pubX, nxt);
    float* tmp = cur; cur = nxt; nxt = tmp;
  }
  // after scans: LX/XR/XZ/XH/W2 dead -> reuse as bf16 fragment buffers (21.5MB region >= 20.5MB)
  ushort* Pf = (ushort*)LX;
  ushort* Af = Pf + (size_t)VT*16*64*8;     // 5,120,000 ushorts each
  float* Xfree = (cur == Xa) ? Xb : Xa;
  ushort* Xf = (ushort*)Xfree;
  hipLaunchKernelGGL(k_packF, dim3(VT), dim3(256), 0, stream, P, Pf);
  hipLaunchKernelGGL(k_packF, dim3(VT), dim3(256), 0, stream, A, Af);
  hipLaunchKernelGGL(k_packF, dim3(128), dim3(256), 0, stream, cur, Xf);
  hipLaunchKernelGGL(k_mlr2, dim3(32,8), dim3(256), 0, stream, Xf, Pf, Af, cur,
                     pp, aa, pa, tgt, pm, tl);
  hipLaunchKernelGGL(k_final, dim3(1), dim3(256), 0, stream, pm, tl, out);
}